// Round 15
// baseline (311.728 us; speedup 1.0000x reference)
//
#include <hip/hip_runtime.h>
#include <hip/hip_bf16.h>

#define B_   2
#define N_   16384
#define H_   8
#define GS_  256
#define NG_  64

typedef unsigned short u16;
typedef __attribute__((ext_vector_type(8))) short bf16x8;
typedef __attribute__((ext_vector_type(4))) float f32x4;
typedef __attribute__((ext_vector_type(8))) unsigned short us8;
typedef __attribute__((ext_vector_type(4))) unsigned short us4;
typedef __attribute__((ext_vector_type(4))) unsigned int u32x4;
typedef __attribute__((ext_vector_type(2))) unsigned int u32x2;

__device__ __forceinline__ u16 f2b(float f){
  union { float f; unsigned u; } v; v.f = f;
  unsigned r = v.u + 0x7fffu + ((v.u >> 16) & 1u);
  return (u16)(r >> 16);
}

__device__ __forceinline__ u16 f2bh(float f){
  __hip_bfloat16 h = __float2bfloat16(f);
  u16 u; __builtin_memcpy(&u, &h, 2);
  return u;
}

// pack two floats into one u32 of 2 bf16 (lo = a, hi = b) — HW packed convert
__device__ __forceinline__ unsigned pk2(float a, float b){
  unsigned r;
  asm("v_cvt_pk_bf16_f32 %0, %1, %2" : "=v"(r) : "v"(a), "v"(b));
  return r;
}

__device__ __forceinline__ void gload16(const void* g, const void* lds){
  __builtin_amdgcn_global_load_lds(
      (const __attribute__((address_space(1))) void*)g,
      (__attribute__((address_space(3))) void*)lds, 16, 0, 0);
}

// swizzled 16B fragment read from a [rows][64] bf16 tile (row stride 128B)
__device__ __forceinline__ bf16x8 lds_read8(const u16* base, int row, int coloff){
  int byte = (row*128 + coloff) ^ ((row & 7) << 4);
  return *(const bf16x8*)((const char*)base + byte);
}

__device__ __forceinline__ void stout(float* p, float v){ *p = v; }
__device__ __forceinline__ void stout(u16* p, float v){ *p = f2b(v); }

// ---------------- fp32 -> bf16 vector convert ----------------
__global__ void cvt_f32_bf16(const float4* __restrict__ in, us4* __restrict__ out, int n4){
  int i = blockIdx.x * 256 + threadIdx.x;
  if (i < n4){
    float4 v = in[i];
    us4 o;
    o[0] = f2b(v.x); o[1] = f2b(v.y); o[2] = f2b(v.z); o[3] = f2b(v.w);
    out[i] = o;
  }
}

// merged small convert: y=0 -> kg, y=1 -> vg (one launch instead of two)
__global__ void cvt_kv(const float4* __restrict__ kg, const float4* __restrict__ vg,
                       us4* __restrict__ ok, us4* __restrict__ ov){
  int i = blockIdx.x * 256 + threadIdx.x;
  const float4* in = blockIdx.y ? vg : kg;
  us4* out = blockIdx.y ? ov : ok;
  float4 v = in[i];
  us4 o;
  o[0] = f2b(v.x); o[1] = f2b(v.y); o[2] = f2b(v.z); o[3] = f2b(v.w);
  out[i] = o;
}

// ---------------- weight convert + transpose: T[n][k] = bf16(W[k][n]) ----------------
__global__ void cvt_w_t(const float* __restrict__ W0, const float* __restrict__ W1,
                        const float* __restrict__ W2, const float* __restrict__ W3,
                        u16* __restrict__ T0, u16* __restrict__ T1,
                        u16* __restrict__ T2, u16* __restrict__ T3)
{
  int z = blockIdx.z;
  const float* W = (z==0)?W0:((z==1)?W1:((z==2)?W2:W3));
  u16* T = (z==0)?T0:((z==1)?T1:((z==2)?T2:T3));
  __shared__ float tile[16][17];
  int tx = threadIdx.x & 15, ty = threadIdx.x >> 4;
  int k0 = blockIdx.x*16, n0 = blockIdx.y*16;
  tile[ty][tx] = W[(k0+ty)*512 + n0 + tx];
  __syncthreads();
  T[(n0+ty)*512 + k0 + tx] = f2b(tile[tx][ty]);
}

// ---------------- bf16 GEMM: C = A @ Wt^T (R8-proven form, bn-fastest grid) ----------------
template<typename OUT_T, bool MULTI, bool GATHA, bool SCATC>
__global__ __launch_bounds__(256, 2) void gemm_bf16k(
    const u16* __restrict__ A,
    const u16* __restrict__ Wt0, const u16* __restrict__ Wt1, const u16* __restrict__ Wt2,
    const int* __restrict__ perm,   // [B][N] permutation
    OUT_T* __restrict__ C, int ldc)
{
  __shared__ u16 Al[128*64];
  __shared__ u16 Bl[128*64];
  const int tid = threadIdx.x;
  const int l = tid & 63, w = tid >> 6;
  const int lr = l & 15, lg = l >> 4;
  const int bm = blockIdx.y, bn = blockIdx.x;   // bn fastest
  const int wr = (w >> 1) * 64, wc = (w & 1) * 64;

  const u16* Wt; int ocolb; float qsc;
  if (MULTI){
    int wsel = bn >> 2;
    Wt = (wsel == 0) ? Wt0 : ((wsel == 1) ? Wt1 : Wt2);
    ocolb = (bn & 3) * 128;
    qsc = (wsel == 0) ? 0.18033688f : 1.0f;   // 0.125 * log2(e)
  } else { Wt = Wt0; ocolb = bn * 128; qsc = 1.0f; }

  // per-thread A-row indices (4 rows), gather-translated once
  int arows[4];
#pragma unroll
  for (int i = 0; i < 4; ++i){
    int r = bm*128 + i*32 + (tid >> 3);
    arows[i] = GATHA ? ((r & ~(N_-1)) + perm[r]) : r;
  }

  f32x4 acc[4][4];
#pragma unroll
  for (int m = 0; m < 4; ++m)
#pragma unroll
    for (int n = 0; n < 4; ++n) acc[m][n] = (f32x4){0.f,0.f,0.f,0.f};

  const int c8 = tid & 7;
  for (int kk = 0; kk < 512; kk += 64){
#pragma unroll
    for (int i = 0; i < 4; ++i){
      int o = i*4096 + tid*16;
      int brow = o >> 7;
      gload16(A  + (size_t)arows[i]*512 + kk + c8*8, (const char*)Al + i*4096 + w*1024);
      gload16(Wt + (size_t)(ocolb + brow)*512 + kk + c8*8, (const char*)Bl + i*4096 + w*1024);
    }
    __syncthreads();
#pragma unroll
    for (int ks = 0; ks < 2; ++ks){
      bf16x8 af[4], bfv[4];
#pragma unroll
      for (int m = 0; m < 4; ++m) af[m]  = *(const bf16x8*)&Al[(wr + m*16 + lr)*64 + ks*32 + lg*8];
#pragma unroll
      for (int n = 0; n < 4; ++n) bfv[n] = *(const bf16x8*)&Bl[(wc + n*16 + lr)*64 + ks*32 + lg*8];
#pragma unroll
      for (int m = 0; m < 4; ++m)
#pragma unroll
        for (int n = 0; n < 4; ++n)
          acc[m][n] = __builtin_amdgcn_mfma_f32_16x16x32_bf16(af[m], bfv[n], acc[m][n], 0, 0, 0);
    }
    __syncthreads();
  }
#pragma unroll
  for (int m = 0; m < 4; ++m)
#pragma unroll
    for (int n = 0; n < 4; ++n)
#pragma unroll
      for (int j = 0; j < 4; ++j){
        int row = bm*128 + wr + m*16 + lg*4 + j;
        int col = bn*128 + wc + n*16 + lr;
        size_t orow = SCATC ? (size_t)((row & ~(N_-1)) + perm[row]) : (size_t)row;
        stout(&C[orow*ldc + col], acc[m][n][j] * qsc);
      }
}

// ---- attention compute, SWAPPED QK, QUARTER-TILE (s_[2][2]=16 regs; R12-proven),
// packed-b64 P stores via HW cvt_pk. PV per 32-row mh half (R13 layouts).
#define COMPUTE_CHUNK(KBUF, VBUF, ACC, LAC) do { \
  _Pragma("unroll") \
  for (int mh_ = 0; mh_ < 2; ++mh_){ \
    _Pragma("unroll") \
    for (int nh_ = 0; nh_ < 2; ++nh_){ \
      f32x4 s_[2][2]; \
      _Pragma("unroll") for (int n2_ = 0; n2_ < 2; ++n2_){ \
        _Pragma("unroll") for (int m2_ = 0; m2_ < 2; ++m2_) s_[n2_][m2_] = (f32x4){0.f,0.f,0.f,0.f}; } \
      _Pragma("unroll") for (int ks_ = 0; ks_ < 2; ++ks_){ \
        bf16x8 kf_[2]; \
        _Pragma("unroll") for (int n2_ = 0; n2_ < 2; ++n2_) \
          kf_[n2_] = lds_read8((KBUF), (nh_*2+n2_)*16 + lr, ks_*64 + lg*16); \
        _Pragma("unroll") for (int n2_ = 0; n2_ < 2; ++n2_){ \
          _Pragma("unroll") for (int m2_ = 0; m2_ < 2; ++m2_) \
            s_[n2_][m2_] = __builtin_amdgcn_mfma_f32_16x16x32_bf16(kf_[n2_], qf[mh_*2+m2_][ks_], s_[n2_][m2_], 0, 0, 0); } } \
      _Pragma("unroll") for (int m2_ = 0; m2_ < 2; ++m2_){ \
        float rs_ = 0.f; \
        int q_ = m2_*16 + lr; \
        _Pragma("unroll") for (int n2_ = 0; n2_ < 2; ++n2_){ \
          _Pragma("unroll") for (int j_ = 0; j_ < 4; ++j_){ \
            float p_ = exp2f(s_[n2_][m2_][j_]); s_[n2_][m2_][j_] = p_; rs_ += p_; } } \
        (LAC)[mh_*2+m2_] += rs_; \
        _Pragma("unroll") for (int n2_ = 0; n2_ < 2; ++n2_){ \
          u32x2 pk_; \
          pk_[0] = pk2(s_[n2_][m2_][0], s_[n2_][m2_][1]); \
          pk_[1] = pk2(s_[n2_][m2_][2], s_[n2_][m2_][3]); \
          int byte_ = (q_*128 + (nh_*2+n2_)*32 + lg*8) ^ ((q_ & 7) << 4); \
          *(u32x2*)((char*)Pw + byte_) = pk_; } } \
    } \
    _Pragma("unroll") for (int ks_ = 0; ks_ < 2; ++ks_){ \
      bf16x8 pa_[2], vb_[4]; \
      _Pragma("unroll") for (int m2_ = 0; m2_ < 2; ++m2_) pa_[m2_] = lds_read8(Pw, m2_*16 + lr, ks_*64 + lg*16); \
      _Pragma("unroll") for (int n_ = 0; n_ < 4; ++n_) vb_[n_] = lds_read8((VBUF), n_*16 + lr, ks_*64 + lg*16); \
      _Pragma("unroll") for (int m2_ = 0; m2_ < 2; ++m2_){ \
        _Pragma("unroll") for (int n_ = 0; n_ < 4; ++n_) \
          (ACC)[mh_*2+m2_][n_] = __builtin_amdgcn_mfma_f32_16x16x32_bf16(pa_[m2_], vb_[n_], (ACC)[mh_*2+m2_][n_], 0, 0, 0); } } \
  } \
} while(0)

// sequential K/V loads into regs (flipped-tail map only bites at g=63)
#define LOADKV(c) do { int c_ = (c); \
  if (c_ < 8){ \
    int p0k_ = g*GS_ + c_*64 + krow_; \
    int p1k_ = p0k_ + 32; \
    int rk0_ = (p0k_ < N_) ? p0k_ : (2*N_ - 1 - p0k_); \
    int rk1_ = (p1k_ < N_) ? p1k_ : (2*N_ - 1 - p1k_); \
    kr0 = *(const us8*)(qkv + (size_t)(b*N_ + rk0_)*1536 + 512 + h*64 + kc8_*8); \
    kr1 = *(const us8*)(qkv + (size_t)(b*N_ + rk1_)*1536 + 512 + h*64 + kc8_*8); \
    int p0v_ = g*GS_ + c_*64 + 2*pair; \
    int p1v_ = p0v_ + 1; \
    int rv0_ = (p0v_ < N_) ? p0v_ : (2*N_ - 1 - p0v_); \
    int rv1_ = (p1v_ < N_) ? p1v_ : (2*N_ - 1 - p1v_); \
    vr0 = *(const us8*)(qkv + (size_t)(b*N_ + rv0_)*1536 + 1024 + h*64 + dvb*8); \
    vr1 = *(const us8*)(qkv + (size_t)(b*N_ + rv1_)*1536 + 1024 + h*64 + dvb*8); \
  } else { \
    kr0 = *(const us8*)(kgb + (size_t)(h*64 + krow_)*64 + kc8_*8); \
    kr1 = *(const us8*)(kgb + (size_t)(h*64 + 32 + krow_)*64 + kc8_*8); \
    vr0 = *(const us8*)(vgb + (size_t)(h*64 + 2*pair)*64 + dvb*8); \
    vr1 = *(const us8*)(vgb + (size_t)(h*64 + 2*pair + 1)*64 + dvb*8); \
  } } while(0)

#define WRITEKV() do { \
  { int r0_ = krow_, r1_ = 32 + krow_; \
    *(us8*)((char*)Kb + ((r0_*128 + kc8_*16) ^ ((r0_ & 7) << 4))) = kr0; \
    *(us8*)((char*)Kb + ((r1_*128 + kc8_*16) ^ ((r1_ & 7) << 4))) = kr1; } \
  _Pragma("unroll") \
  for (int j_ = 0; j_ < 8; ++j_){ \
    int r_ = dvb*8 + j_; \
    int byte_ = (r_*128 + pair*4) ^ ((r_ & 7) << 4); \
    *(unsigned*)((char*)Vb + byte_) = (unsigned)vr0[j_] | ((unsigned)vr1[j_] << 16); } \
} while(0)

// ---------------- fused local(512-window) + global(64) attention ----------------
// R13 base (32KB LDS, single K/V buffer, 2 barriers/chunk, FETCH=90MB proven)
// + quarter-tile QK (s_ 64->16 regs) + launch_bounds(256,3): total unified
// regs ~160 <= 170 budget -> 3 waves/SIMD. Global chunk is TWO-PASS (rowsum
// pass then recompute+scale+pack) to keep the register peak at loop level.
__global__ __launch_bounds__(256, 3) void attn_kernel(
    const u16* __restrict__ qkv,   // [B*N][1536] bf16, permuted order (q pre-scaled)
    const u16* __restrict__ kgb,   // [H][64][64] bf16
    const u16* __restrict__ vgb,   // [H][64][64] bf16
    u16* __restrict__ outp)        // [B*N][512] bf16, permuted order
{
  __shared__ u16 Pl[4][32*64];     // 16KB wave-private P / out staging (4KB each)
  __shared__ u16 Kb[64*64];        // 8KB swizzled
  __shared__ u16 Vb[64*64];        // 8KB transposed [dv][t], swizzled

  const int tid = threadIdx.x;
  const int l = tid & 63, w = tid >> 6;
  const int lr = l & 15, lg = l >> 4;
  const int pair = tid & 31, dvb = tid >> 5;
  const int krow_ = tid >> 3, kc8_ = tid & 7;

  const int g = blockIdx.x, h = blockIdx.y, b = blockIdx.z;

  // ---- Q fragments straight to registers ----
  bf16x8 qf[4][2];
#pragma unroll
  for (int m = 0; m < 4; ++m){
    int grow = g*GS_ + w*64 + m*16 + lr;
    const u16* qrow = qkv + (size_t)(b*N_ + grow)*1536 + h*64;
#pragma unroll
    for (int ks = 0; ks < 2; ++ks)
      qf[m][ks] = *(const bf16x8*)(qrow + ks*32 + lg*8);
  }

  u16* Pw = Pl[w];                       // wave-private 4KB [32][64] region

  us8 kr0, kr1, vr0, vr1;
  LOADKV(0);
  WRITEKV();                             // one-time exposed vmcnt wait
  __syncthreads();                       // chunk 0 visible

  f32x4 oacc[4][4];
  float lrun[4];
#pragma unroll
  for (int m = 0; m < 4; ++m)
#pragma unroll
    for (int n = 0; n < 4; ++n) oacc[m][n] = (f32x4){0.f,0.f,0.f,0.f};
#pragma unroll
  for (int m = 0; m < 4; ++m) lrun[m] = 0.f;

  for (int c = 0; c < 8; ++c){
    LOADKV(c + 1);                       // c==7 loads global K/V; in flight across compute
    COMPUTE_CHUNK(Kb, Vb, oacc, lrun);
    __syncthreads();                     // all waves done reading Kb/Vb
    WRITEKV();                           // vmcnt wait covered by the compute above
    __syncthreads();                     // next chunk visible
  }

  // ---- finalize local softmax: reduce lane-partial sums, broadcast, divide ----
  float i1[4];
#pragma unroll
  for (int m = 0; m < 4; ++m){
    float s1 = lrun[m];
    s1 += __shfl_xor(s1, 16); s1 += __shfl_xor(s1, 32);
    i1[m] = 1.f / s1;
  }
#pragma unroll
  for (int m = 0; m < 4; ++m)
#pragma unroll
    for (int j = 0; j < 4; ++j){
      float invb = __shfl(i1[m], lg*4 + j);
#pragma unroll
      for (int n = 0; n < 4; ++n) oacc[m][n][j] *= invb;
    }

  // ---- global-attention chunk (chunk 8, resident in Kb/Vb), TWO-PASS quarter-tile ----
  {
    float rsg[4] = {0.f, 0.f, 0.f, 0.f};
    // pass 1: rowsums only (quarter s_ discarded; ~16 extra MFMAs, free at 15% MfmaUtil)
#pragma unroll
    for (int mh_ = 0; mh_ < 2; ++mh_)
#pragma unroll
      for (int nh_ = 0; nh_ < 2; ++nh_){
        f32x4 s_[2][2];
#pragma unroll
        for (int n2_ = 0; n2_ < 2; ++n2_)
#pragma unroll
          for (int m2_ = 0; m2_ < 2; ++m2_) s_[n2_][m2_] = (f32x4){0.f,0.f,0.f,0.f};
#pragma unroll
        for (int ks_ = 0; ks_ < 2; ++ks_){
          bf16x8 kf_[2];
#pragma unroll
          for (int n2_ = 0; n2_ < 2; ++n2_)
            kf_[n2_] = lds_read8(Kb, (nh_*2+n2_)*16 + lr, ks_*64 + lg*16);
#pragma unroll
          for (int n2_ = 0; n2_ < 2; ++n2_)
#pragma unroll
            for (int m2_ = 0; m2_ < 2; ++m2_)
              s_[n2_][m2_] = __builtin_amdgcn_mfma_f32_16x16x32_bf16(kf_[n2_], qf[mh_*2+m2_][ks_], s_[n2_][m2_], 0, 0, 0);
        }
#pragma unroll
        for (int m2_ = 0; m2_ < 2; ++m2_)
#pragma unroll
          for (int n2_ = 0; n2_ < 2; ++n2_)
#pragma unroll
            for (int j_ = 0; j_ < 4; ++j_)
              rsg[mh_*2+m2_] += exp2f(s_[n2_][m2_][j_]);
      }
#pragma unroll
    for (int m = 0; m < 4; ++m){
      float s2 = rsg[m];
      s2 += __shfl_xor(s2, 16); s2 += __shfl_xor(s2, 32);
      rsg[m] = 1.f / s2;                 // lane-uniform for q = m*16 + lr
    }
    // pass 2: recompute, scale by 1/rs, pack, PV per mh half
#pragma unroll
    for (int mh_ = 0; mh_ < 2; ++mh_){
#pragma unroll
      for (int nh_ = 0; nh_ < 2; ++nh_){
        f32x4 s_[2][2];
#pragma unroll
        for (int n2_ = 0; n2_ < 2; ++n2_)
#pragma unroll
          for (int m2_ = 0; m2_ < 2; ++m2_) s_[n2_][m2_] = (f32x4){0.f,0.f,0.f,0.f};
#pragma unroll
        for (int ks_ = 0; ks_ < 2; ++ks_){
          bf16x8 kf_[2];
#pragma unroll
          for (int n2_ = 0; n2_ < 2; ++n2_)
            kf_[n2_] = lds_read8(Kb, (nh_*2+n2_)*16 + lr, ks_*64 + lg*16);
#pragma unroll
          for (int n2_ = 0; n2_ < 2; ++n2_)
#pragma unroll
            for (int m2_ = 0; m2_ < 2; ++m2_)
              s_[n2_][m2_] = __builtin_amdgcn_mfma_f32_16x16x32_bf16(kf_[n2_], qf[mh_*2+m2_][ks_], s_[n2_][m2_], 0, 0, 0);
        }
#pragma unroll
        for (int m2_ = 0; m2_ < 2; ++m2_){
          float iv_ = rsg[mh_*2+m2_];
          int q_ = m2_*16 + lr;
#pragma unroll
          for (int n2_ = 0; n2_ < 2; ++n2_){
            u32x2 pk_;
            pk_[0] = pk2(exp2f(s_[n2_][m2_][0])*iv_, exp2f(s_[n2_][m2_][1])*iv_);
            pk_[1] = pk2(exp2f(s_[n2_][m2_][2])*iv_, exp2f(s_[n2_][m2_][3])*iv_);
            int byte_ = (q_*128 + (nh_*2+n2_)*32 + lg*8) ^ ((q_ & 7) << 4);
            *(u32x2*)((char*)Pw + byte_) = pk_;
          }
        }
      }
#pragma unroll
      for (int ks_ = 0; ks_ < 2; ++ks_){
        bf16x8 pa_[2], vb_[4];
#pragma unroll
        for (int m2_ = 0; m2_ < 2; ++m2_) pa_[m2_] = lds_read8(Pw, m2_*16 + lr, ks_*64 + lg*16);
#pragma unroll
        for (int n_ = 0; n_ < 4; ++n_) vb_[n_] = lds_read8(Vb, n_*16 + lr, ks_*64 + lg*16);
#pragma unroll
        for (int m2_ = 0; m2_ < 2; ++m2_)
#pragma unroll
          for (int n_ = 0; n_ < 4; ++n_)
            oacc[mh_*2+m2_][n_] = __builtin_amdgcn_mfma_f32_16x16x32_bf16(pa_[m2_], vb_[n_], oacc[mh_*2+m2_][n_], 0, 0, 0);
      }
    }
  }

  // ---- epilogue: stage half to LDS, coalesced sequential write, twice ----
#pragma unroll
  for (int mh = 0; mh < 2; ++mh){
#pragma unroll
    for (int m2 = 0; m2 < 2; ++m2)
#pragma unroll
      for (int n = 0; n < 4; ++n)
#pragma unroll
        for (int j = 0; j < 4; ++j){
          int row = m2*16 + lg*4 + j, col = n*16 + lr;
          int byte = (row*128 + col*2) ^ ((row & 7) << 4);
          *(u16*)((char*)Pw + byte) = f2bh(oacc[mh*2+m2][n][j]);
        }
    __builtin_amdgcn_s_waitcnt(0);  // drain before re-reading wave-private Pw
#pragma unroll
    for (int i4 = 0; i4 < 4; ++i4){
      int o = i4*1024 + l*16;
      int row = o >> 7, c8 = (o & 127) >> 4;
      int addr = o ^ ((row & 7) << 4);
      u32x4 d = *(const u32x4*)((const char*)Pw + addr);
      int orow = g*GS_ + w*64 + mh*32 + row;
      *(u32x4*)(outp + (size_t)(b*N_ + orow)*512 + h*64 + c8*8) = d;
    }
  }
}

extern "C" void kernel_launch(void* const* d_in, const int* in_sizes, int n_in,
                              void* d_out, int out_size, void* d_ws, size_t ws_size,
                              hipStream_t stream)
{
  const float* x  = (const float*)d_in[0];
  const int*  idx = (const int*)d_in[1];
  const float* kg = (const float*)d_in[2];
  const float* vg = (const float*)d_in[3];
  const float* Wq = (const float*)d_in[4];
  const float* Wk = (const float*)d_in[5];
  const float* Wv = (const float*)d_in[6];
  const float* Wp = (const float*)d_in[7];
  float* out = (float*)d_out;

  char* ws = (char*)d_ws;
  u16* Xb   = (u16*)ws;                                   // reused as attn_o
  u16* qkv  = (u16*)(ws + 33554432);
  u16* Wqt  = (u16*)(ws + 134217728);
  u16* Wkt  = (u16*)(ws + 134217728 + 524288);
  u16* Wvt  = (u16*)(ws + 134217728 + 2*524288);
  u16* Wpt  = (u16*)(ws + 134217728 + 3*524288);
  u16* kgb  = (u16*)(ws + 134217728 + 4*524288);
  u16* vgb  = (u16*)(ws + 134217728 + 4*524288 + 65536);
  u16* attn_o = Xb;  // safe: gemm_qkv (reads Xb) completes before attn writes

  cvt_f32_bf16<<<16384, 256, 0, stream>>>((const float4*)x, (us4*)Xb, 16777216/4);
  cvt_kv<<<dim3(32,2), 256, 0, stream>>>((const float4*)kg, (const float4*)vg,
                                         (us4*)kgb, (us4*)vgb);
  cvt_w_t<<<dim3(32,32,4), 256, 0, stream>>>(Wq, Wk, Wv, Wp, Wqt, Wkt, Wvt, Wpt);
  // qkv GEMM: bn-fastest grid; gathers A-rows via idx -> qkv in PERMUTED order
  gemm_bf16k<u16, true, true, false><<<dim3(12,256), 256, 0, stream>>>(Xb, Wqt, Wkt, Wvt, idx, qkv, 1536);
  // attention: quarter-tile QK + forced 3-wave/SIMD occupancy
  attn_kernel<<<dim3(64,8,2), 256, 0, stream>>>(qkv, kgb, vgb, attn_o);
  // proj GEMM: bn-fastest grid; scatters C-rows via idx -> token order
  gemm_bf16k<float, false, false, true><<<dim3(4,256), 256, 0, stream>>>(attn_o, Wpt, Wpt, Wpt, idx, out, 512);
}

// Round 16
// 227.881 us; speedup vs baseline: 1.3679x; 1.3679x over previous
//
#include <hip/hip_runtime.h>
#include <hip/hip_bf16.h>

#define B_   2
#define N_   16384
#define H_   8
#define GS_  256
#define NG_  64

typedef unsigned short u16;
typedef __attribute__((ext_vector_type(8))) short bf16x8;
typedef __attribute__((ext_vector_type(4))) float f32x4;
typedef __attribute__((ext_vector_type(8))) unsigned short us8;
typedef __attribute__((ext_vector_type(4))) unsigned short us4;
typedef __attribute__((ext_vector_type(4))) unsigned int u32x4;
typedef __attribute__((ext_vector_type(2))) unsigned int u32x2;

__device__ __forceinline__ u16 f2b(float f){
  union { float f; unsigned u; } v; v.f = f;
  unsigned r = v.u + 0x7fffu + ((v.u >> 16) & 1u);
  return (u16)(r >> 16);
}

__device__ __forceinline__ u16 f2bh(float f){
  __hip_bfloat16 h = __float2bfloat16(f);
  u16 u; __builtin_memcpy(&u, &h, 2);
  return u;
}

// pack two floats into one u32 of 2 bf16 (lo = a, hi = b) — HW packed convert
__device__ __forceinline__ unsigned pk2(float a, float b){
  unsigned r;
  asm("v_cvt_pk_bf16_f32 %0, %1, %2" : "=v"(r) : "v"(a), "v"(b));
  return r;
}

__device__ __forceinline__ void gload16(const void* g, const void* lds){
  __builtin_amdgcn_global_load_lds(
      (const __attribute__((address_space(1))) void*)g,
      (__attribute__((address_space(3))) void*)lds, 16, 0, 0);
}

// swizzled 16B fragment read from a [rows][64] bf16 tile (row stride 128B)
__device__ __forceinline__ bf16x8 lds_read8(const u16* base, int row, int coloff){
  int byte = (row*128 + coloff) ^ ((row & 7) << 4);
  return *(const bf16x8*)((const char*)base + byte);
}

__device__ __forceinline__ void stout(float* p, float v){ *p = v; }
__device__ __forceinline__ void stout(u16* p, float v){ *p = f2b(v); }

// merged small convert: y=0 -> kg, y=1 -> vg (one launch instead of two)
__global__ void cvt_kv(const float4* __restrict__ kg, const float4* __restrict__ vg,
                       us4* __restrict__ ok, us4* __restrict__ ov){
  int i = blockIdx.x * 256 + threadIdx.x;
  const float4* in = blockIdx.y ? vg : kg;
  us4* out = blockIdx.y ? ov : ok;
  float4 v = in[i];
  us4 o;
  o[0] = f2b(v.x); o[1] = f2b(v.y); o[2] = f2b(v.z); o[3] = f2b(v.w);
  out[i] = o;
}

// ---------------- weight convert + transpose: T[n][k] = bf16(W[k][n]) ----------------
__global__ void cvt_w_t(const float* __restrict__ W0, const float* __restrict__ W1,
                        const float* __restrict__ W2, const float* __restrict__ W3,
                        u16* __restrict__ T0, u16* __restrict__ T1,
                        u16* __restrict__ T2, u16* __restrict__ T3)
{
  int z = blockIdx.z;
  const float* W = (z==0)?W0:((z==1)?W1:((z==2)?W2:W3));
  u16* T = (z==0)?T0:((z==1)?T1:((z==2)?T2:T3));
  __shared__ float tile[16][17];
  int tx = threadIdx.x & 15, ty = threadIdx.x >> 4;
  int k0 = blockIdx.x*16, n0 = blockIdx.y*16;
  tile[ty][tx] = W[(k0+ty)*512 + n0 + tx];
  __syncthreads();
  T[(n0+ty)*512 + k0 + tx] = f2b(tile[tx][ty]);
}

// ---------------- bf16 GEMM: C = A @ Wt^T (R8-proven form, bn-fastest grid) ----------------
// AF32: A is fp32; reg-stage float4x2 -> v_cvt_pk_bf16_f32 x4 -> ds_write_b128
//       (fuses the x f32->bf16 pass into the GEMM; B path keeps global_load_lds).
// GATHA: A-rows gathered through perm. SCATC: C-rows scattered through perm.
template<typename OUT_T, bool MULTI, bool GATHA, bool SCATC, bool AF32>
__global__ __launch_bounds__(256, 2) void gemm_bf16k(
    const void* __restrict__ Araw,
    const u16* __restrict__ Wt0, const u16* __restrict__ Wt1, const u16* __restrict__ Wt2,
    const int* __restrict__ perm,   // [B][N] permutation
    OUT_T* __restrict__ C, int ldc)
{
  __shared__ u16 Al[128*64];
  __shared__ u16 Bl[128*64];
  const int tid = threadIdx.x;
  const int l = tid & 63, w = tid >> 6;
  const int lr = l & 15, lg = l >> 4;
  const int bm = blockIdx.y, bn = blockIdx.x;   // bn fastest
  const int wr = (w >> 1) * 64, wc = (w & 1) * 64;

  const u16* Wt; int ocolb; float qsc;
  if (MULTI){
    int wsel = bn >> 2;
    Wt = (wsel == 0) ? Wt0 : ((wsel == 1) ? Wt1 : Wt2);
    ocolb = (bn & 3) * 128;
    qsc = (wsel == 0) ? 0.18033688f : 1.0f;   // 0.125 * log2(e)
  } else { Wt = Wt0; ocolb = bn * 128; qsc = 1.0f; }

  // per-thread A-row indices (4 rows), gather-translated once
  int arows[4];
#pragma unroll
  for (int i = 0; i < 4; ++i){
    int r = bm*128 + i*32 + (tid >> 3);
    arows[i] = GATHA ? ((r & ~(N_-1)) + perm[r]) : r;
  }

  f32x4 acc[4][4];
#pragma unroll
  for (int m = 0; m < 4; ++m)
#pragma unroll
    for (int n = 0; n < 4; ++n) acc[m][n] = (f32x4){0.f,0.f,0.f,0.f};

  const int c8 = tid & 7;
  for (int kk = 0; kk < 512; kk += 64){
#pragma unroll
    for (int i = 0; i < 4; ++i){
      if (AF32){
        const float* As = (const float*)Araw + (size_t)arows[i]*512 + kk + c8*8;
        float4 f0 = *(const float4*)As;
        float4 f1 = *(const float4*)(As + 4);
        us8 o;
        unsigned* op = (unsigned*)&o;
        op[0] = pk2(f0.x, f0.y); op[1] = pk2(f0.z, f0.w);
        op[2] = pk2(f1.x, f1.y); op[3] = pk2(f1.z, f1.w);
        *(us8*)((char*)Al + i*4096 + tid*16) = o;
      } else {
        gload16((const u16*)Araw + (size_t)arows[i]*512 + kk + c8*8,
                (const char*)Al + i*4096 + w*1024);
      }
      int o2 = i*4096 + tid*16;
      int brow = o2 >> 7;
      gload16(Wt + (size_t)(ocolb + brow)*512 + kk + c8*8, (const char*)Bl + i*4096 + w*1024);
    }
    __syncthreads();
#pragma unroll
    for (int ks = 0; ks < 2; ++ks){
      bf16x8 af[4], bfv[4];
#pragma unroll
      for (int m = 0; m < 4; ++m) af[m]  = *(const bf16x8*)&Al[(wr + m*16 + lr)*64 + ks*32 + lg*8];
#pragma unroll
      for (int n = 0; n < 4; ++n) bfv[n] = *(const bf16x8*)&Bl[(wc + n*16 + lr)*64 + ks*32 + lg*8];
#pragma unroll
      for (int m = 0; m < 4; ++m)
#pragma unroll
        for (int n = 0; n < 4; ++n)
          acc[m][n] = __builtin_amdgcn_mfma_f32_16x16x32_bf16(af[m], bfv[n], acc[m][n], 0, 0, 0);
    }
    __syncthreads();
  }
#pragma unroll
  for (int m = 0; m < 4; ++m)
#pragma unroll
    for (int n = 0; n < 4; ++n)
#pragma unroll
      for (int j = 0; j < 4; ++j){
        int row = bm*128 + wr + m*16 + lg*4 + j;
        int col = bn*128 + wc + n*16 + lr;
        size_t orow = SCATC ? (size_t)((row & ~(N_-1)) + perm[row]) : (size_t)row;
        stout(&C[orow*ldc + col], acc[m][n][j] * qsc);
      }
}

// ---- attention compute, SWAPPED QK (S^T = mfma(K,Q)) + packed-b64 P stores ----
#define COMPUTE_CHUNK(KBUF, VBUF, ACC, LAC) do { \
  f32x4 s_[4][4]; \
  _Pragma("unroll") \
  for (int n_ = 0; n_ < 4; ++n_){ _Pragma("unroll") for (int m_ = 0; m_ < 4; ++m_) s_[n_][m_] = (f32x4){0.f,0.f,0.f,0.f}; } \
  _Pragma("unroll") \
  for (int ks_ = 0; ks_ < 2; ++ks_){ \
    bf16x8 kf_[4]; \
    _Pragma("unroll") for (int n_ = 0; n_ < 4; ++n_) kf_[n_] = lds_read8((KBUF), n_*16 + lr, ks_*64 + lg*16); \
    _Pragma("unroll") for (int n_ = 0; n_ < 4; ++n_){ \
      _Pragma("unroll") for (int m_ = 0; m_ < 4; ++m_) \
        s_[n_][m_] = __builtin_amdgcn_mfma_f32_16x16x32_bf16(kf_[n_], qf[m_][ks_], s_[n_][m_], 0, 0, 0); } } \
  _Pragma("unroll") \
  for (int m_ = 0; m_ < 4; ++m_){ \
    float rs_ = 0.f; \
    _Pragma("unroll") for (int n_ = 0; n_ < 4; ++n_){ \
      _Pragma("unroll") for (int j_ = 0; j_ < 4; ++j_){ \
        float p_ = exp2f(s_[n_][m_][j_]); s_[n_][m_][j_] = p_; rs_ += p_; } } \
    (LAC)[m_] += rs_; } \
  _Pragma("unroll") \
  for (int mh_ = 0; mh_ < 2; ++mh_){ \
    _Pragma("unroll") for (int m2_ = 0; m2_ < 2; ++m2_){ \
      int m_ = mh_*2 + m2_; \
      int q_ = m2_*16 + lr; \
      _Pragma("unroll") for (int n_ = 0; n_ < 4; ++n_){ \
        u32x2 pk_; \
        pk_[0] = pk2(s_[n_][m_][0], s_[n_][m_][1]); \
        pk_[1] = pk2(s_[n_][m_][2], s_[n_][m_][3]); \
        int byte_ = (q_*128 + n_*32 + lg*8) ^ ((q_ & 7) << 4); \
        *(u32x2*)((char*)Pw + byte_) = pk_; } } \
    _Pragma("unroll") for (int ks_ = 0; ks_ < 2; ++ks_){ \
      bf16x8 pa_[2], vb_[4]; \
      _Pragma("unroll") for (int m2_ = 0; m2_ < 2; ++m2_) pa_[m2_] = lds_read8(Pw, m2_*16 + lr, ks_*64 + lg*16); \
      _Pragma("unroll") for (int n_ = 0; n_ < 4; ++n_) vb_[n_] = lds_read8((VBUF), n_*16 + lr, ks_*64 + lg*16); \
      _Pragma("unroll") for (int m2_ = 0; m2_ < 2; ++m2_){ \
        _Pragma("unroll") for (int n_ = 0; n_ < 4; ++n_) \
          (ACC)[mh_*2+m2_][n_] = __builtin_amdgcn_mfma_f32_16x16x32_bf16(pa_[m2_], vb_[n_], (ACC)[mh_*2+m2_][n_], 0, 0, 0); } } \
  } \
} while(0)

// sequential K/V loads into regs (flipped-tail map only bites at g=63)
#define LOADKV(c) do { int c_ = (c); \
  if (c_ < 8){ \
    int p0k_ = g*GS_ + c_*64 + krow_; \
    int p1k_ = p0k_ + 32; \
    int rk0_ = (p0k_ < N_) ? p0k_ : (2*N_ - 1 - p0k_); \
    int rk1_ = (p1k_ < N_) ? p1k_ : (2*N_ - 1 - p1k_); \
    kr0 = *(const us8*)(qkv + (size_t)(b*N_ + rk0_)*1536 + 512 + h*64 + kc8_*8); \
    kr1 = *(const us8*)(qkv + (size_t)(b*N_ + rk1_)*1536 + 512 + h*64 + kc8_*8); \
    int p0v_ = g*GS_ + c_*64 + 2*pair; \
    int p1v_ = p0v_ + 1; \
    int rv0_ = (p0v_ < N_) ? p0v_ : (2*N_ - 1 - p0v_); \
    int rv1_ = (p1v_ < N_) ? p1v_ : (2*N_ - 1 - p1v_); \
    vr0 = *(const us8*)(qkv + (size_t)(b*N_ + rv0_)*1536 + 1024 + h*64 + dvb*8); \
    vr1 = *(const us8*)(qkv + (size_t)(b*N_ + rv1_)*1536 + 1024 + h*64 + dvb*8); \
  } else { \
    kr0 = *(const us8*)(kgb + (size_t)(h*64 + krow_)*64 + kc8_*8); \
    kr1 = *(const us8*)(kgb + (size_t)(h*64 + 32 + krow_)*64 + kc8_*8); \
    vr0 = *(const us8*)(vgb + (size_t)(h*64 + 2*pair)*64 + dvb*8); \
    vr1 = *(const us8*)(vgb + (size_t)(h*64 + 2*pair + 1)*64 + dvb*8); \
  } } while(0)

#define WRITEKV() do { \
  { int r0_ = krow_, r1_ = 32 + krow_; \
    *(us8*)((char*)Kb + ((r0_*128 + kc8_*16) ^ ((r0_ & 7) << 4))) = kr0; \
    *(us8*)((char*)Kb + ((r1_*128 + kc8_*16) ^ ((r1_ & 7) << 4))) = kr1; } \
  _Pragma("unroll") \
  for (int j_ = 0; j_ < 8; ++j_){ \
    int r_ = dvb*8 + j_; \
    int byte_ = (r_*128 + pair*4) ^ ((r_ & 7) << 4); \
    *(unsigned*)((char*)Vb + byte_) = (unsigned)vr0[j_] | ((unsigned)vr1[j_] << 16); } \
} while(0)

// ---------------- fused local(512-window) + global(64) attention ----------------
// R13/R14 structure EXACTLY (current best: 101us attn; 32KB LDS, single K/V
// buffer, 2 barriers/chunk, HW cvt_pk P-pack, launch_bounds(256,2)).
// Occupancy is structurally capped (~190 unified regs/wave); 3-wave budget
// spills (verified R4/R10/R15) — do not retry.
__global__ __launch_bounds__(256, 2) void attn_kernel(
    const u16* __restrict__ qkv,   // [B*N][1536] bf16, permuted order (q pre-scaled)
    const u16* __restrict__ kgb,   // [H][64][64] bf16
    const u16* __restrict__ vgb,   // [H][64][64] bf16
    u16* __restrict__ outp)        // [B*N][512] bf16, permuted order
{
  __shared__ u16 Pl[4][32*64];     // 16KB wave-private P / out staging (4KB each)
  __shared__ u16 Kb[64*64];        // 8KB swizzled
  __shared__ u16 Vb[64*64];        // 8KB transposed [dv][t], swizzled

  const int tid = threadIdx.x;
  const int l = tid & 63, w = tid >> 6;
  const int lr = l & 15, lg = l >> 4;
  const int pair = tid & 31, dvb = tid >> 5;
  const int krow_ = tid >> 3, kc8_ = tid & 7;

  const int g = blockIdx.x, h = blockIdx.y, b = blockIdx.z;

  // ---- Q fragments straight to registers ----
  bf16x8 qf[4][2];
#pragma unroll
  for (int m = 0; m < 4; ++m){
    int grow = g*GS_ + w*64 + m*16 + lr;
    const u16* qrow = qkv + (size_t)(b*N_ + grow)*1536 + h*64;
#pragma unroll
    for (int ks = 0; ks < 2; ++ks)
      qf[m][ks] = *(const bf16x8*)(qrow + ks*32 + lg*8);
  }

  u16* Pw = Pl[w];                       // wave-private 4KB [32][64] region

  us8 kr0, kr1, vr0, vr1;
  LOADKV(0);
  WRITEKV();                             // one-time exposed vmcnt wait
  __syncthreads();                       // chunk 0 visible

  f32x4 oacc[4][4];
  float lrun[4];
#pragma unroll
  for (int m = 0; m < 4; ++m)
#pragma unroll
    for (int n = 0; n < 4; ++n) oacc[m][n] = (f32x4){0.f,0.f,0.f,0.f};
#pragma unroll
  for (int m = 0; m < 4; ++m) lrun[m] = 0.f;

  for (int c = 0; c < 8; ++c){
    LOADKV(c + 1);                       // c==7 loads global K/V; in flight across compute
    COMPUTE_CHUNK(Kb, Vb, oacc, lrun);
    __syncthreads();                     // all waves done reading Kb/Vb
    WRITEKV();                           // vmcnt wait covered by the compute above
    __syncthreads();                     // next chunk visible
  }

  // ---- finalize local softmax: reduce lane-partial sums, broadcast, divide ----
  float i1[4];
#pragma unroll
  for (int m = 0; m < 4; ++m){
    float s1 = lrun[m];
    s1 += __shfl_xor(s1, 16); s1 += __shfl_xor(s1, 32);
    i1[m] = 1.f / s1;
  }
#pragma unroll
  for (int m = 0; m < 4; ++m)
#pragma unroll
    for (int j = 0; j < 4; ++j){
      float invb = __shfl(i1[m], lg*4 + j);
#pragma unroll
      for (int n = 0; n < 4; ++n) oacc[m][n][j] *= invb;
    }

  // ---- global-attention chunk (chunk 8, resident in Kb/Vb); swapped QK,
  //      lane-uniform inline normalize, accumulate into oacc ----
  {
    f32x4 s_[4][4];
#pragma unroll
    for (int n_ = 0; n_ < 4; ++n_)
#pragma unroll
      for (int m_ = 0; m_ < 4; ++m_) s_[n_][m_] = (f32x4){0.f,0.f,0.f,0.f};
#pragma unroll
    for (int ks_ = 0; ks_ < 2; ++ks_){
      bf16x8 kf_[4];
#pragma unroll
      for (int n_ = 0; n_ < 4; ++n_) kf_[n_] = lds_read8(Kb, n_*16 + lr, ks_*64 + lg*16);
#pragma unroll
      for (int n_ = 0; n_ < 4; ++n_)
#pragma unroll
        for (int m_ = 0; m_ < 4; ++m_)
          s_[n_][m_] = __builtin_amdgcn_mfma_f32_16x16x32_bf16(kf_[n_], qf[m_][ks_], s_[n_][m_], 0, 0, 0);
    }
#pragma unroll
    for (int m_ = 0; m_ < 4; ++m_){
      float rs_ = 0.f;
#pragma unroll
      for (int n_ = 0; n_ < 4; ++n_)
#pragma unroll
        for (int j_ = 0; j_ < 4; ++j_){
          float p_ = exp2f(s_[n_][m_][j_]); s_[n_][m_][j_] = p_; rs_ += p_;
        }
      rs_ += __shfl_xor(rs_, 16); rs_ += __shfl_xor(rs_, 32);
      float iv_ = 1.f / rs_;               // lane-uniform for q = m*16 + lr
#pragma unroll
      for (int n_ = 0; n_ < 4; ++n_)
#pragma unroll
        for (int j_ = 0; j_ < 4; ++j_) s_[n_][m_][j_] *= iv_;
    }
#pragma unroll
    for (int mh_ = 0; mh_ < 2; ++mh_){
#pragma unroll
      for (int m2_ = 0; m2_ < 2; ++m2_){
        int m_ = mh_*2 + m2_;
        int q_ = m2_*16 + lr;
#pragma unroll
        for (int n_ = 0; n_ < 4; ++n_){
          u32x2 pk_;
          pk_[0] = pk2(s_[n_][m_][0], s_[n_][m_][1]);
          pk_[1] = pk2(s_[n_][m_][2], s_[n_][m_][3]);
          int byte_ = (q_*128 + n_*32 + lg*8) ^ ((q_ & 7) << 4);
          *(u32x2*)((char*)Pw + byte_) = pk_;
        }
      }
#pragma unroll
      for (int ks_ = 0; ks_ < 2; ++ks_){
        bf16x8 pa_[2], vb_[4];
#pragma unroll
        for (int m2_ = 0; m2_ < 2; ++m2_) pa_[m2_] = lds_read8(Pw, m2_*16 + lr, ks_*64 + lg*16);
#pragma unroll
        for (int n_ = 0; n_ < 4; ++n_) vb_[n_] = lds_read8(Vb, n_*16 + lr, ks_*64 + lg*16);
#pragma unroll
        for (int m2_ = 0; m2_ < 2; ++m2_)
#pragma unroll
          for (int n_ = 0; n_ < 4; ++n_)
            oacc[mh_*2+m2_][n_] = __builtin_amdgcn_mfma_f32_16x16x32_bf16(pa_[m2_], vb_[n_], oacc[mh_*2+m2_][n_], 0, 0, 0);
      }
    }
  }

  // ---- epilogue: stage half to LDS, coalesced sequential write, twice ----
#pragma unroll
  for (int mh = 0; mh < 2; ++mh){
#pragma unroll
    for (int m2 = 0; m2 < 2; ++m2)
#pragma unroll
      for (int n = 0; n < 4; ++n)
#pragma unroll
        for (int j = 0; j < 4; ++j){
          int row = m2*16 + lg*4 + j, col = n*16 + lr;
          int byte = (row*128 + col*2) ^ ((row & 7) << 4);
          *(u16*)((char*)Pw + byte) = f2bh(oacc[mh*2+m2][n][j]);
        }
    __builtin_amdgcn_s_waitcnt(0);  // drain before re-reading wave-private Pw
#pragma unroll
    for (int i4 = 0; i4 < 4; ++i4){
      int o = i4*1024 + l*16;
      int row = o >> 7, c8 = (o & 127) >> 4;
      int addr = o ^ ((row & 7) << 4);
      u32x4 d = *(const u32x4*)((const char*)Pw + addr);
      int orow = g*GS_ + w*64 + mh*32 + row;
      *(u32x4*)(outp + (size_t)(b*N_ + orow)*512 + h*64 + c8*8) = d;
    }
  }
}

extern "C" void kernel_launch(void* const* d_in, const int* in_sizes, int n_in,
                              void* d_out, int out_size, void* d_ws, size_t ws_size,
                              hipStream_t stream)
{
  const float* x  = (const float*)d_in[0];
  const int*  idx = (const int*)d_in[1];
  const float* kg = (const float*)d_in[2];
  const float* vg = (const float*)d_in[3];
  const float* Wq = (const float*)d_in[4];
  const float* Wk = (const float*)d_in[5];
  const float* Wv = (const float*)d_in[6];
  const float* Wp = (const float*)d_in[7];
  float* out = (float*)d_out;

  char* ws = (char*)d_ws;
  u16* attn_o = (u16*)ws;                                 // 33,554,432 B
  u16* qkv  = (u16*)(ws + 33554432);
  u16* Wqt  = (u16*)(ws + 134217728);
  u16* Wkt  = (u16*)(ws + 134217728 + 524288);
  u16* Wvt  = (u16*)(ws + 134217728 + 2*524288);
  u16* Wpt  = (u16*)(ws + 134217728 + 3*524288);
  u16* kgb  = (u16*)(ws + 134217728 + 4*524288);
  u16* vgb  = (u16*)(ws + 134217728 + 4*524288 + 65536);

  cvt_kv<<<dim3(32,2), 256, 0, stream>>>((const float4*)kg, (const float4*)vg,
                                         (us4*)kgb, (us4*)vgb);
  cvt_w_t<<<dim3(32,32,4), 256, 0, stream>>>(Wq, Wk, Wv, Wp, Wqt, Wkt, Wvt, Wpt);
  // qkv GEMM: reads x (f32) directly, converts in A-staging via v_cvt_pk;
  // gathers A-rows via idx -> qkv in PERMUTED order (q pre-scaled 0.125*log2e)
  gemm_bf16k<u16, true, true, false, true><<<dim3(12,256), 256, 0, stream>>>(
      x, Wqt, Wkt, Wvt, idx, qkv, 1536);
  // attention: R14 structure (best measured)
  attn_kernel<<<dim3(64,8,2), 256, 0, stream>>>(qkv, kgb, vgb, attn_o);
  // proj GEMM: bn-fastest grid; scatters C-rows via idx -> token order
  gemm_bf16k<float, false, false, true, false><<<dim3(4,256), 256, 0, stream>>>(
      attn_o, Wpt, Wpt, Wpt, idx, out, 512);
}

// Round 17
// 214.172 us; speedup vs baseline: 1.4555x; 1.0640x over previous
//
#include <hip/hip_runtime.h>
#include <hip/hip_bf16.h>

#define B_   2
#define N_   16384
#define H_   8
#define GS_  256
#define NG_  64

typedef unsigned short u16;
typedef __attribute__((ext_vector_type(8))) short bf16x8;
typedef __attribute__((ext_vector_type(4))) float f32x4;
typedef __attribute__((ext_vector_type(8))) unsigned short us8;
typedef __attribute__((ext_vector_type(4))) unsigned short us4;
typedef __attribute__((ext_vector_type(4))) unsigned int u32x4;
typedef __attribute__((ext_vector_type(2))) unsigned int u32x2;

__device__ __forceinline__ u16 f2b(float f){
  union { float f; unsigned u; } v; v.f = f;
  unsigned r = v.u + 0x7fffu + ((v.u >> 16) & 1u);
  return (u16)(r >> 16);
}

__device__ __forceinline__ u16 f2bh(float f){
  __hip_bfloat16 h = __float2bfloat16(f);
  u16 u; __builtin_memcpy(&u, &h, 2);
  return u;
}

// pack two floats into one u32 of 2 bf16 (lo = a, hi = b) — HW packed convert
__device__ __forceinline__ unsigned pk2(float a, float b){
  unsigned r;
  asm("v_cvt_pk_bf16_f32 %0, %1, %2" : "=v"(r) : "v"(a), "v"(b));
  return r;
}

__device__ __forceinline__ void gload16(const void* g, const void* lds){
  __builtin_amdgcn_global_load_lds(
      (const __attribute__((address_space(1))) void*)g,
      (__attribute__((address_space(3))) void*)lds, 16, 0, 0);
}

// swizzled 16B fragment read from a [rows][64] bf16 tile (row stride 128B)
__device__ __forceinline__ bf16x8 lds_read8(const u16* base, int row, int coloff){
  int byte = (row*128 + coloff) ^ ((row & 7) << 4);
  return *(const bf16x8*)((const char*)base + byte);
}

__device__ __forceinline__ void stout(float* p, float v){ *p = v; }
__device__ __forceinline__ void stout(u16* p, float v){ *p = f2b(v); }

// ---------------- fp32 -> bf16 vector convert (x) ----------------
__global__ void cvt_f32_bf16(const float4* __restrict__ in, us4* __restrict__ out, int n4){
  int i = blockIdx.x * 256 + threadIdx.x;
  if (i < n4){
    float4 v = in[i];
    us4 o;
    o[0] = f2b(v.x); o[1] = f2b(v.y); o[2] = f2b(v.z); o[3] = f2b(v.w);
    out[i] = o;
  }
}

// merged small convert: y=0 -> kg, y=1 -> vg
__global__ void cvt_kv(const float4* __restrict__ kg, const float4* __restrict__ vg,
                       us4* __restrict__ ok, us4* __restrict__ ov){
  int i = blockIdx.x * 256 + threadIdx.x;
  const float4* in = blockIdx.y ? vg : kg;
  us4* out = blockIdx.y ? ov : ok;
  float4 v = in[i];
  us4 o;
  o[0] = f2b(v.x); o[1] = f2b(v.y); o[2] = f2b(v.z); o[3] = f2b(v.w);
  out[i] = o;
}

// ---------------- weight convert + transpose: T[n][k] = bf16(W[k][n]) ----------------
__global__ void cvt_w_t(const float* __restrict__ W0, const float* __restrict__ W1,
                        const float* __restrict__ W2, const float* __restrict__ W3,
                        u16* __restrict__ T0, u16* __restrict__ T1,
                        u16* __restrict__ T2, u16* __restrict__ T3)
{
  int z = blockIdx.z;
  const float* W = (z==0)?W0:((z==1)?W1:((z==2)?W2:W3));
  u16* T = (z==0)?T0:((z==1)?T1:((z==2)?T2:T3));
  __shared__ float tile[16][17];
  int tx = threadIdx.x & 15, ty = threadIdx.x >> 4;
  int k0 = blockIdx.x*16, n0 = blockIdx.y*16;
  tile[ty][tx] = W[(k0+ty)*512 + n0 + tx];
  __syncthreads();
  T[(n0+ty)*512 + k0 + tx] = f2b(tile[tx][ty]);
}

// ---------------- bf16 GEMM: C = A @ Wt^T ----------------
// T3-minimal 2-phase: DOUBLE-BUFFERED LDS, stage(t+1) issued BEFORE compute(t),
// ONE barrier per K-step (loads fly across the whole compute phase before the
// drain). LDS 64KB; occupancy VGPR-capped at 2 blocks/CU either way -> free.
// bn-fastest grid. GATHA: A-rows gathered via perm. SCATC: C-rows scattered.
template<typename OUT_T, bool MULTI, bool GATHA, bool SCATC>
__global__ __launch_bounds__(256, 2) void gemm_bf16k(
    const u16* __restrict__ A,
    const u16* __restrict__ Wt0, const u16* __restrict__ Wt1, const u16* __restrict__ Wt2,
    const int* __restrict__ perm,   // [B][N] permutation
    OUT_T* __restrict__ C, int ldc)
{
  __shared__ u16 Al[2][128*64];
  __shared__ u16 Bl[2][128*64];
  const int tid = threadIdx.x;
  const int l = tid & 63, w = tid >> 6;
  const int lr = l & 15, lg = l >> 4;
  const int bm = blockIdx.y, bn = blockIdx.x;   // bn fastest
  const int wr = (w >> 1) * 64, wc = (w & 1) * 64;

  const u16* Wt; int ocolb; float qsc;
  if (MULTI){
    int wsel = bn >> 2;
    Wt = (wsel == 0) ? Wt0 : ((wsel == 1) ? Wt1 : Wt2);
    ocolb = (bn & 3) * 128;
    qsc = (wsel == 0) ? 0.18033688f : 1.0f;   // 0.125 * log2(e)
  } else { Wt = Wt0; ocolb = bn * 128; qsc = 1.0f; }

  // per-thread A-row indices (4 rows), gather-translated once
  int arows[4];
#pragma unroll
  for (int i = 0; i < 4; ++i){
    int r = bm*128 + i*32 + (tid >> 3);
    arows[i] = GATHA ? ((r & ~(N_-1)) + perm[r]) : r;
  }

  const int c8 = tid & 7;

#define G_ISSUE(T, BI) do { int kk_ = (T)*64; \
  _Pragma("unroll") \
  for (int i_ = 0; i_ < 4; ++i_){ \
    int o_ = i_*4096 + tid*16; \
    int brow_ = o_ >> 7; \
    gload16(A  + (size_t)arows[i_]*512 + kk_ + c8*8, (const char*)Al[BI] + i_*4096 + w*1024); \
    gload16(Wt + (size_t)(ocolb + brow_)*512 + kk_ + c8*8, (const char*)Bl[BI] + i_*4096 + w*1024); \
  } } while(0)

  f32x4 acc[4][4];
#pragma unroll
  for (int m = 0; m < 4; ++m)
#pragma unroll
    for (int n = 0; n < 4; ++n) acc[m][n] = (f32x4){0.f,0.f,0.f,0.f};

  G_ISSUE(0, 0);
  __syncthreads();                        // tile 0 resident

  for (int t = 0; t < 8; ++t){
    int cur = t & 1;
    if (t < 7) G_ISSUE(t + 1, cur ^ 1);   // in flight across compute below
#pragma unroll
    for (int ks = 0; ks < 2; ++ks){
      bf16x8 af[4], bfv[4];
#pragma unroll
      for (int m = 0; m < 4; ++m) af[m]  = *(const bf16x8*)&Al[cur][(wr + m*16 + lr)*64 + ks*32 + lg*8];
#pragma unroll
      for (int n = 0; n < 4; ++n) bfv[n] = *(const bf16x8*)&Bl[cur][(wc + n*16 + lr)*64 + ks*32 + lg*8];
#pragma unroll
      for (int m = 0; m < 4; ++m)
#pragma unroll
        for (int n = 0; n < 4; ++n)
          acc[m][n] = __builtin_amdgcn_mfma_f32_16x16x32_bf16(af[m], bfv[n], acc[m][n], 0, 0, 0);
    }
    __syncthreads();                      // drains t+1 loads (aged by compute); syncs reads
  }
#undef G_ISSUE

#pragma unroll
  for (int m = 0; m < 4; ++m)
#pragma unroll
    for (int n = 0; n < 4; ++n)
#pragma unroll
      for (int j = 0; j < 4; ++j){
        int row = bm*128 + wr + m*16 + lg*4 + j;
        int col = bn*128 + wc + n*16 + lr;
        size_t orow = SCATC ? (size_t)((row & ~(N_-1)) + perm[row]) : (size_t)row;
        stout(&C[orow*ldc + col], acc[m][n][j] * qsc);
      }
}

// ---- attention compute, SWAPPED QK (S^T = mfma(K,Q)) + packed-b64 P stores ----
#define COMPUTE_CHUNK(KBUF, VBUF, ACC, LAC) do { \
  f32x4 s_[4][4]; \
  _Pragma("unroll") \
  for (int n_ = 0; n_ < 4; ++n_){ _Pragma("unroll") for (int m_ = 0; m_ < 4; ++m_) s_[n_][m_] = (f32x4){0.f,0.f,0.f,0.f}; } \
  _Pragma("unroll") \
  for (int ks_ = 0; ks_ < 2; ++ks_){ \
    bf16x8 kf_[4]; \
    _Pragma("unroll") for (int n_ = 0; n_ < 4; ++n_) kf_[n_] = lds_read8((KBUF), n_*16 + lr, ks_*64 + lg*16); \
    _Pragma("unroll") for (int n_ = 0; n_ < 4; ++n_){ \
      _Pragma("unroll") for (int m_ = 0; m_ < 4; ++m_) \
        s_[n_][m_] = __builtin_amdgcn_mfma_f32_16x16x32_bf16(kf_[n_], qf[m_][ks_], s_[n_][m_], 0, 0, 0); } } \
  _Pragma("unroll") \
  for (int m_ = 0; m_ < 4; ++m_){ \
    float rs_ = 0.f; \
    _Pragma("unroll") for (int n_ = 0; n_ < 4; ++n_){ \
      _Pragma("unroll") for (int j_ = 0; j_ < 4; ++j_){ \
        float p_ = exp2f(s_[n_][m_][j_]); s_[n_][m_][j_] = p_; rs_ += p_; } } \
    (LAC)[m_] += rs_; } \
  _Pragma("unroll") \
  for (int mh_ = 0; mh_ < 2; ++mh_){ \
    _Pragma("unroll") for (int m2_ = 0; m2_ < 2; ++m2_){ \
      int m_ = mh_*2 + m2_; \
      int q_ = m2_*16 + lr; \
      _Pragma("unroll") for (int n_ = 0; n_ < 4; ++n_){ \
        u32x2 pk_; \
        pk_[0] = pk2(s_[n_][m_][0], s_[n_][m_][1]); \
        pk_[1] = pk2(s_[n_][m_][2], s_[n_][m_][3]); \
        int byte_ = (q_*128 + n_*32 + lg*8) ^ ((q_ & 7) << 4); \
        *(u32x2*)((char*)Pw + byte_) = pk_; } } \
    _Pragma("unroll") for (int ks_ = 0; ks_ < 2; ++ks_){ \
      bf16x8 pa_[2], vb_[4]; \
      _Pragma("unroll") for (int m2_ = 0; m2_ < 2; ++m2_) pa_[m2_] = lds_read8(Pw, m2_*16 + lr, ks_*64 + lg*16); \
      _Pragma("unroll") for (int n_ = 0; n_ < 4; ++n_) vb_[n_] = lds_read8((VBUF), n_*16 + lr, ks_*64 + lg*16); \
      _Pragma("unroll") for (int m2_ = 0; m2_ < 2; ++m2_){ \
        _Pragma("unroll") for (int n_ = 0; n_ < 4; ++n_) \
          (ACC)[mh_*2+m2_][n_] = __builtin_amdgcn_mfma_f32_16x16x32_bf16(pa_[m2_], vb_[n_], (ACC)[mh_*2+m2_][n_], 0, 0, 0); } } \
  } \
} while(0)

// sequential K/V loads into regs (flipped-tail map only bites at g=63)
#define LOADKV(c) do { int c_ = (c); \
  if (c_ < 8){ \
    int p0k_ = g*GS_ + c_*64 + krow_; \
    int p1k_ = p0k_ + 32; \
    int rk0_ = (p0k_ < N_) ? p0k_ : (2*N_ - 1 - p0k_); \
    int rk1_ = (p1k_ < N_) ? p1k_ : (2*N_ - 1 - p1k_); \
    kr0 = *(const us8*)(qkv + (size_t)(b*N_ + rk0_)*1536 + 512 + h*64 + kc8_*8); \
    kr1 = *(const us8*)(qkv + (size_t)(b*N_ + rk1_)*1536 + 512 + h*64 + kc8_*8); \
    int p0v_ = g*GS_ + c_*64 + 2*pair; \
    int p1v_ = p0v_ + 1; \
    int rv0_ = (p0v_ < N_) ? p0v_ : (2*N_ - 1 - p0v_); \
    int rv1_ = (p1v_ < N_) ? p1v_ : (2*N_ - 1 - p1v_); \
    vr0 = *(const us8*)(qkv + (size_t)(b*N_ + rv0_)*1536 + 1024 + h*64 + dvb*8); \
    vr1 = *(const us8*)(qkv + (size_t)(b*N_ + rv1_)*1536 + 1024 + h*64 + dvb*8); \
  } else { \
    kr0 = *(const us8*)(kgb + (size_t)(h*64 + krow_)*64 + kc8_*8); \
    kr1 = *(const us8*)(kgb + (size_t)(h*64 + 32 + krow_)*64 + kc8_*8); \
    vr0 = *(const us8*)(vgb + (size_t)(h*64 + 2*pair)*64 + dvb*8); \
    vr1 = *(const us8*)(vgb + (size_t)(h*64 + 2*pair + 1)*64 + dvb*8); \
  } } while(0)

#define WRITEKV() do { \
  { int r0_ = krow_, r1_ = 32 + krow_; \
    *(us8*)((char*)Kb + ((r0_*128 + kc8_*16) ^ ((r0_ & 7) << 4))) = kr0; \
    *(us8*)((char*)Kb + ((r1_*128 + kc8_*16) ^ ((r1_ & 7) << 4))) = kr1; } \
  _Pragma("unroll") \
  for (int j_ = 0; j_ < 8; ++j_){ \
    int r_ = dvb*8 + j_; \
    int byte_ = (r_*128 + pair*4) ^ ((r_ & 7) << 4); \
    *(unsigned*)((char*)Vb + byte_) = (unsigned)vr0[j_] | ((unsigned)vr1[j_] << 16); } \
} while(0)

// ---------------- fused local(512-window) + global(64) attention ----------------
// R13/R14 structure EXACTLY (best measured: 101us attn). Occupancy structurally
// capped (~190 unified regs/wave); 3-wave budget spills (R4/R10/R15) — do not retry.
__global__ __launch_bounds__(256, 2) void attn_kernel(
    const u16* __restrict__ qkv,   // [B*N][1536] bf16, permuted order (q pre-scaled)
    const u16* __restrict__ kgb,   // [H][64][64] bf16
    const u16* __restrict__ vgb,   // [H][64][64] bf16
    u16* __restrict__ outp)        // [B*N][512] bf16, permuted order
{
  __shared__ u16 Pl[4][32*64];     // 16KB wave-private P / out staging (4KB each)
  __shared__ u16 Kb[64*64];        // 8KB swizzled
  __shared__ u16 Vb[64*64];        // 8KB transposed [dv][t], swizzled

  const int tid = threadIdx.x;
  const int l = tid & 63, w = tid >> 6;
  const int lr = l & 15, lg = l >> 4;
  const int pair = tid & 31, dvb = tid >> 5;
  const int krow_ = tid >> 3, kc8_ = tid & 7;

  const int g = blockIdx.x, h = blockIdx.y, b = blockIdx.z;

  // ---- Q fragments straight to registers ----
  bf16x8 qf[4][2];
#pragma unroll
  for (int m = 0; m < 4; ++m){
    int grow = g*GS_ + w*64 + m*16 + lr;
    const u16* qrow = qkv + (size_t)(b*N_ + grow)*1536 + h*64;
#pragma unroll
    for (int ks = 0; ks < 2; ++ks)
      qf[m][ks] = *(const bf16x8*)(qrow + ks*32 + lg*8);
  }

  u16* Pw = Pl[w];                       // wave-private 4KB [32][64] region

  us8 kr0, kr1, vr0, vr1;
  LOADKV(0);
  WRITEKV();                             // one-time exposed vmcnt wait
  __syncthreads();                       // chunk 0 visible

  f32x4 oacc[4][4];
  float lrun[4];
#pragma unroll
  for (int m = 0; m < 4; ++m)
#pragma unroll
    for (int n = 0; n < 4; ++n) oacc[m][n] = (f32x4){0.f,0.f,0.f,0.f};
#pragma unroll
  for (int m = 0; m < 4; ++m) lrun[m] = 0.f;

  for (int c = 0; c < 8; ++c){
    LOADKV(c + 1);                       // c==7 loads global K/V; in flight across compute
    COMPUTE_CHUNK(Kb, Vb, oacc, lrun);
    __syncthreads();                     // all waves done reading Kb/Vb
    WRITEKV();                           // vmcnt wait covered by the compute above
    __syncthreads();                     // next chunk visible
  }

  // ---- finalize local softmax: reduce lane-partial sums, broadcast, divide ----
  float i1[4];
#pragma unroll
  for (int m = 0; m < 4; ++m){
    float s1 = lrun[m];
    s1 += __shfl_xor(s1, 16); s1 += __shfl_xor(s1, 32);
    i1[m] = 1.f / s1;
  }
#pragma unroll
  for (int m = 0; m < 4; ++m)
#pragma unroll
    for (int j = 0; j < 4; ++j){
      float invb = __shfl(i1[m], lg*4 + j);
#pragma unroll
      for (int n = 0; n < 4; ++n) oacc[m][n][j] *= invb;
    }

  // ---- global-attention chunk (chunk 8, resident in Kb/Vb); swapped QK,
  //      lane-uniform inline normalize, accumulate into oacc ----
  {
    f32x4 s_[4][4];
#pragma unroll
    for (int n_ = 0; n_ < 4; ++n_)
#pragma unroll
      for (int m_ = 0; m_ < 4; ++m_) s_[n_][m_] = (f32x4){0.f,0.f,0.f,0.f};
#pragma unroll
    for (int ks_ = 0; ks_ < 2; ++ks_){
      bf16x8 kf_[4];
#pragma unroll
      for (int n_ = 0; n_ < 4; ++n_) kf_[n_] = lds_read8(Kb, n_*16 + lr, ks_*64 + lg*16);
#pragma unroll
      for (int n_ = 0; n_ < 4; ++n_)
#pragma unroll
        for (int m_ = 0; m_ < 4; ++m_)
          s_[n_][m_] = __builtin_amdgcn_mfma_f32_16x16x32_bf16(kf_[n_], qf[m_][ks_], s_[n_][m_], 0, 0, 0);
    }
#pragma unroll
    for (int m_ = 0; m_ < 4; ++m_){
      float rs_ = 0.f;
#pragma unroll
      for (int n_ = 0; n_ < 4; ++n_)
#pragma unroll
        for (int j_ = 0; j_ < 4; ++j_){
          float p_ = exp2f(s_[n_][m_][j_]); s_[n_][m_][j_] = p_; rs_ += p_;
        }
      rs_ += __shfl_xor(rs_, 16); rs_ += __shfl_xor(rs_, 32);
      float iv_ = 1.f / rs_;               // lane-uniform for q = m*16 + lr
#pragma unroll
      for (int n_ = 0; n_ < 4; ++n_)
#pragma unroll
        for (int j_ = 0; j_ < 4; ++j_) s_[n_][m_][j_] *= iv_;
    }
#pragma unroll
    for (int mh_ = 0; mh_ < 2; ++mh_){
#pragma unroll
      for (int m2_ = 0; m2_ < 2; ++m2_){
        int m_ = mh_*2 + m2_;
        int q_ = m2_*16 + lr;
#pragma unroll
        for (int n_ = 0; n_ < 4; ++n_){
          u32x2 pk_;
          pk_[0] = pk2(s_[n_][m_][0], s_[n_][m_][1]);
          pk_[1] = pk2(s_[n_][m_][2], s_[n_][m_][3]);
          int byte_ = (q_*128 + n_*32 + lg*8) ^ ((q_ & 7) << 4);
          *(u32x2*)((char*)Pw + byte_) = pk_;
        }
      }
#pragma unroll
      for (int ks_ = 0; ks_ < 2; ++ks_){
        bf16x8 pa_[2], vb_[4];
#pragma unroll
        for (int m2_ = 0; m2_ < 2; ++m2_) pa_[m2_] = lds_read8(Pw, m2_*16 + lr, ks_*64 + lg*16);
#pragma unroll
        for (int n_ = 0; n_ < 4; ++n_) vb_[n_] = lds_read8(Vb, n_*16 + lr, ks_*64 + lg*16);
#pragma unroll
        for (int m2_ = 0; m2_ < 2; ++m2_)
#pragma unroll
          for (int n_ = 0; n_ < 4; ++n_)
            oacc[mh_*2+m2_][n_] = __builtin_amdgcn_mfma_f32_16x16x32_bf16(pa_[m2_], vb_[n_], oacc[mh_*2+m2_][n_], 0, 0, 0);
      }
    }
  }

  // ---- epilogue: stage half to LDS, coalesced sequential write, twice ----
#pragma unroll
  for (int mh = 0; mh < 2; ++mh){
#pragma unroll
    for (int m2 = 0; m2 < 2; ++m2)
#pragma unroll
      for (int n = 0; n < 4; ++n)
#pragma unroll
        for (int j = 0; j < 4; ++j){
          int row = m2*16 + lg*4 + j, col = n*16 + lr;
          int byte = (row*128 + col*2) ^ ((row & 7) << 4);
          *(u16*)((char*)Pw + byte) = f2bh(oacc[mh*2+m2][n][j]);
        }
    __builtin_amdgcn_s_waitcnt(0);  // drain before re-reading wave-private Pw
#pragma unroll
    for (int i4 = 0; i4 < 4; ++i4){
      int o = i4*1024 + l*16;
      int row = o >> 7, c8 = (o & 127) >> 4;
      int addr = o ^ ((row & 7) << 4);
      u32x4 d = *(const u32x4*)((const char*)Pw + addr);
      int orow = g*GS_ + w*64 + mh*32 + row;
      *(u32x4*)(outp + (size_t)(b*N_ + orow)*512 + h*64 + c8*8) = d;
    }
  }
}

extern "C" void kernel_launch(void* const* d_in, const int* in_sizes, int n_in,
                              void* d_out, int out_size, void* d_ws, size_t ws_size,
                              hipStream_t stream)
{
  const float* x  = (const float*)d_in[0];
  const int*  idx = (const int*)d_in[1];
  const float* kg = (const float*)d_in[2];
  const float* vg = (const float*)d_in[3];
  const float* Wq = (const float*)d_in[4];
  const float* Wk = (const float*)d_in[5];
  const float* Wv = (const float*)d_in[6];
  const float* Wp = (const float*)d_in[7];
  float* out = (float*)d_out;

  char* ws = (char*)d_ws;
  u16* Xb   = (u16*)ws;                                   // reused as attn_o
  u16* qkv  = (u16*)(ws + 33554432);
  u16* Wqt  = (u16*)(ws + 134217728);
  u16* Wkt  = (u16*)(ws + 134217728 + 524288);
  u16* Wvt  = (u16*)(ws + 134217728 + 2*524288);
  u16* Wpt  = (u16*)(ws + 134217728 + 3*524288);
  u16* kgb  = (u16*)(ws + 134217728 + 4*524288);
  u16* vgb  = (u16*)(ws + 134217728 + 4*524288 + 65536);
  u16* attn_o = Xb;  // safe: gemm_qkv (reads Xb) completes before attn writes

  cvt_f32_bf16<<<16384, 256, 0, stream>>>((const float4*)x, (us4*)Xb, 16777216/4);
  cvt_kv<<<dim3(32,2), 256, 0, stream>>>((const float4*)kg, (const float4*)vg,
                                         (us4*)kgb, (us4*)vgb);
  cvt_w_t<<<dim3(32,32,4), 256, 0, stream>>>(Wq, Wk, Wv, Wp, Wqt, Wkt, Wvt, Wpt);
  // qkv GEMM: bn-fastest grid, dbuf prefetch; gathers A-rows via idx
  gemm_bf16k<u16, true, true, false><<<dim3(12,256), 256, 0, stream>>>(Xb, Wqt, Wkt, Wvt, idx, qkv, 1536);
  // attention: R14 structure (best measured)
  attn_kernel<<<dim3(64,8,2), 256, 0, stream>>>(qkv, kgb, vgb, attn_o);
  // proj GEMM: bn-fastest grid, dbuf prefetch; scatters C-rows via idx
  gemm_bf16k<float, false, false, true><<<dim3(4,256), 256, 0, stream>>>(attn_o, Wpt, Wpt, Wpt, idx, out, 512);
}

// Round 18
// 211.129 us; speedup vs baseline: 1.4765x; 1.0144x over previous
//
#include <hip/hip_runtime.h>
#include <hip/hip_bf16.h>

#define B_   2
#define N_   16384
#define H_   8
#define GS_  256
#define NG_  64

typedef unsigned short u16;
typedef __attribute__((ext_vector_type(8))) short bf16x8;
typedef __attribute__((ext_vector_type(4))) float f32x4;
typedef __attribute__((ext_vector_type(8))) unsigned short us8;
typedef __attribute__((ext_vector_type(4))) unsigned short us4;
typedef __attribute__((ext_vector_type(4))) unsigned int u32x4;
typedef __attribute__((ext_vector_type(2))) unsigned int u32x2;

__device__ __forceinline__ u16 f2b(float f){
  union { float f; unsigned u; } v; v.f = f;
  unsigned r = v.u + 0x7fffu + ((v.u >> 16) & 1u);
  return (u16)(r >> 16);
}

__device__ __forceinline__ u16 f2bh(float f){
  __hip_bfloat16 h = __float2bfloat16(f);
  u16 u; __builtin_memcpy(&u, &h, 2);
  return u;
}

// pack two floats into one u32 of 2 bf16 (lo = a, hi = b) — HW packed convert
__device__ __forceinline__ unsigned pk2(float a, float b){
  unsigned r;
  asm("v_cvt_pk_bf16_f32 %0, %1, %2" : "=v"(r) : "v"(a), "v"(b));
  return r;
}

__device__ __forceinline__ void gload16(const void* g, const void* lds){
  __builtin_amdgcn_global_load_lds(
      (const __attribute__((address_space(1))) void*)g,
      (__attribute__((address_space(3))) void*)lds, 16, 0, 0);
}

// swizzled 16B fragment read from a [rows][64] bf16 tile (row stride 128B)
__device__ __forceinline__ bf16x8 lds_read8(const u16* base, int row, int coloff){
  int byte = (row*128 + coloff) ^ ((row & 7) << 4);
  return *(const bf16x8*)((const char*)base + byte);
}

__device__ __forceinline__ void stout(float* p, float v){ *p = v; }
__device__ __forceinline__ void stout(u16* p, float v){ *p = f2b(v); }

// ---------------- fp32 -> bf16 vector convert (x) ----------------
__global__ void cvt_f32_bf16(const float4* __restrict__ in, us4* __restrict__ out, int n4){
  int i = blockIdx.x * 256 + threadIdx.x;
  if (i < n4){
    float4 v = in[i];
    us4 o;
    o[0] = f2b(v.x); o[1] = f2b(v.y); o[2] = f2b(v.z); o[3] = f2b(v.w);
    out[i] = o;
  }
}

// merged small convert: y=0 -> kg, y=1 -> vg
__global__ void cvt_kv(const float4* __restrict__ kg, const float4* __restrict__ vg,
                       us4* __restrict__ ok, us4* __restrict__ ov){
  int i = blockIdx.x * 256 + threadIdx.x;
  const float4* in = blockIdx.y ? vg : kg;
  us4* out = blockIdx.y ? ov : ok;
  float4 v = in[i];
  us4 o;
  o[0] = f2b(v.x); o[1] = f2b(v.y); o[2] = f2b(v.z); o[3] = f2b(v.w);
  out[i] = o;
}

// ---------------- weight convert + transpose: T[n][k] = bf16(W[k][n]) ----------------
__global__ void cvt_w_t(const float* __restrict__ W0, const float* __restrict__ W1,
                        const float* __restrict__ W2, const float* __restrict__ W3,
                        u16* __restrict__ T0, u16* __restrict__ T1,
                        u16* __restrict__ T2, u16* __restrict__ T3)
{
  int z = blockIdx.z;
  const float* W = (z==0)?W0:((z==1)?W1:((z==2)?W2:W3));
  u16* T = (z==0)?T0:((z==1)?T1:((z==2)?T2:T3));
  __shared__ float tile[16][17];
  int tx = threadIdx.x & 15, ty = threadIdx.x >> 4;
  int k0 = blockIdx.x*16, n0 = blockIdx.y*16;
  tile[ty][tx] = W[(k0+ty)*512 + n0 + tx];
  __syncthreads();
  T[(n0+ty)*512 + k0 + tx] = f2b(tile[tx][ty]);
}

// ---------------- bf16 GEMM: C = A @ Wt^T ----------------
// BK=32 DOUBLE-BUFFER: 2x(8+8)KB = 32KB LDS total (same as single-buffer best
// -> keeps 4 blocks/CU) while tile t+1's loads fly across tile t's 16-MFMA
// compute phase before the single per-step barrier. bn-fastest grid.
// GATHA: A-rows gathered via perm. SCATC: C-rows scattered via perm.
template<typename OUT_T, bool MULTI, bool GATHA, bool SCATC>
__global__ __launch_bounds__(256, 2) void gemm_bf16k(
    const u16* __restrict__ A,
    const u16* __restrict__ Wt0, const u16* __restrict__ Wt1, const u16* __restrict__ Wt2,
    const int* __restrict__ perm,   // [B][N] permutation
    OUT_T* __restrict__ C, int ldc)
{
  __shared__ u16 Al[2][128*32];
  __shared__ u16 Bl[2][128*32];
  const int tid = threadIdx.x;
  const int l = tid & 63, w = tid >> 6;
  const int lr = l & 15, lg = l >> 4;
  const int bm = blockIdx.y, bn = blockIdx.x;   // bn fastest
  const int wr = (w >> 1) * 64, wc = (w & 1) * 64;

  const u16* Wt; int ocolb; float qsc;
  if (MULTI){
    int wsel = bn >> 2;
    Wt = (wsel == 0) ? Wt0 : ((wsel == 1) ? Wt1 : Wt2);
    ocolb = (bn & 3) * 128;
    qsc = (wsel == 0) ? 0.18033688f : 1.0f;   // 0.125 * log2(e)
  } else { Wt = Wt0; ocolb = bn * 128; qsc = 1.0f; }

  // per-thread A/B row indices (2 rows each; BK=32 -> 4 chunks/row)
  const int rr = tid >> 2;          // 0..63
  const int c4 = tid & 3;           // 16B chunk within the 64B k-row
  int arows[2], brows[2];
#pragma unroll
  for (int i = 0; i < 2; ++i){
    int r = bm*128 + i*64 + rr;
    arows[i] = GATHA ? ((r & ~(N_-1)) + perm[r]) : r;
    brows[i] = ocolb + i*64 + rr;
  }

#define G_ISSUE(T, BI) do { int kk_ = (T)*32; \
  _Pragma("unroll") \
  for (int i_ = 0; i_ < 2; ++i_){ \
    gload16(A  + (size_t)arows[i_]*512 + kk_ + c4*8, (const char*)Al[BI] + i_*4096 + w*1024); \
    gload16(Wt + (size_t)brows[i_]*512 + kk_ + c4*8, (const char*)Bl[BI] + i_*4096 + w*1024); \
  } } while(0)

  f32x4 acc[4][4];
#pragma unroll
  for (int m = 0; m < 4; ++m)
#pragma unroll
    for (int n = 0; n < 4; ++n) acc[m][n] = (f32x4){0.f,0.f,0.f,0.f};

  G_ISSUE(0, 0);
  __syncthreads();                        // tile 0 resident

  for (int t = 0; t < 16; ++t){
    int cur = t & 1;
    if (t < 15) G_ISSUE(t + 1, cur ^ 1);  // in flight across the compute below
    bf16x8 af[4], bfv[4];
#pragma unroll
    for (int m = 0; m < 4; ++m) af[m]  = *(const bf16x8*)&Al[cur][(wr + m*16 + lr)*32 + lg*8];
#pragma unroll
    for (int n = 0; n < 4; ++n) bfv[n] = *(const bf16x8*)&Bl[cur][(wc + n*16 + lr)*32 + lg*8];
#pragma unroll
    for (int m = 0; m < 4; ++m)
#pragma unroll
      for (int n = 0; n < 4; ++n)
        acc[m][n] = __builtin_amdgcn_mfma_f32_16x16x32_bf16(af[m], bfv[n], acc[m][n], 0, 0, 0);
    __syncthreads();                      // drains t+1 loads (aged by compute); syncs reads
  }
#undef G_ISSUE

#pragma unroll
  for (int m = 0; m < 4; ++m)
#pragma unroll
    for (int n = 0; n < 4; ++n)
#pragma unroll
      for (int j = 0; j < 4; ++j){
        int row = bm*128 + wr + m*16 + lg*4 + j;
        int col = bn*128 + wc + n*16 + lr;
        size_t orow = SCATC ? (size_t)((row & ~(N_-1)) + perm[row]) : (size_t)row;
        stout(&C[orow*ldc + col], acc[m][n][j] * qsc);
      }
}

// ---- attention compute, SWAPPED QK (S^T = mfma(K,Q)) + packed-b64 P stores ----
#define COMPUTE_CHUNK(KBUF, VBUF, ACC, LAC) do { \
  f32x4 s_[4][4]; \
  _Pragma("unroll") \
  for (int n_ = 0; n_ < 4; ++n_){ _Pragma("unroll") for (int m_ = 0; m_ < 4; ++m_) s_[n_][m_] = (f32x4){0.f,0.f,0.f,0.f}; } \
  _Pragma("unroll") \
  for (int ks_ = 0; ks_ < 2; ++ks_){ \
    bf16x8 kf_[4]; \
    _Pragma("unroll") for (int n_ = 0; n_ < 4; ++n_) kf_[n_] = lds_read8((KBUF), n_*16 + lr, ks_*64 + lg*16); \
    _Pragma("unroll") for (int n_ = 0; n_ < 4; ++n_){ \
      _Pragma("unroll") for (int m_ = 0; m_ < 4; ++m_) \
        s_[n_][m_] = __builtin_amdgcn_mfma_f32_16x16x32_bf16(kf_[n_], qf[m_][ks_], s_[n_][m_], 0, 0, 0); } } \
  _Pragma("unroll") \
  for (int m_ = 0; m_ < 4; ++m_){ \
    float rs_ = 0.f; \
    _Pragma("unroll") for (int n_ = 0; n_ < 4; ++n_){ \
      _Pragma("unroll") for (int j_ = 0; j_ < 4; ++j_){ \
        float p_ = exp2f(s_[n_][m_][j_]); s_[n_][m_][j_] = p_; rs_ += p_; } } \
    (LAC)[m_] += rs_; } \
  _Pragma("unroll") \
  for (int mh_ = 0; mh_ < 2; ++mh_){ \
    _Pragma("unroll") for (int m2_ = 0; m2_ < 2; ++m2_){ \
      int m_ = mh_*2 + m2_; \
      int q_ = m2_*16 + lr; \
      _Pragma("unroll") for (int n_ = 0; n_ < 4; ++n_){ \
        u32x2 pk_; \
        pk_[0] = pk2(s_[n_][m_][0], s_[n_][m_][1]); \
        pk_[1] = pk2(s_[n_][m_][2], s_[n_][m_][3]); \
        int byte_ = (q_*128 + n_*32 + lg*8) ^ ((q_ & 7) << 4); \
        *(u32x2*)((char*)Pw + byte_) = pk_; } } \
    _Pragma("unroll") for (int ks_ = 0; ks_ < 2; ++ks_){ \
      bf16x8 pa_[2], vb_[4]; \
      _Pragma("unroll") for (int m2_ = 0; m2_ < 2; ++m2_) pa_[m2_] = lds_read8(Pw, m2_*16 + lr, ks_*64 + lg*16); \
      _Pragma("unroll") for (int n_ = 0; n_ < 4; ++n_) vb_[n_] = lds_read8((VBUF), n_*16 + lr, ks_*64 + lg*16); \
      _Pragma("unroll") for (int m2_ = 0; m2_ < 2; ++m2_){ \
        _Pragma("unroll") for (int n_ = 0; n_ < 4; ++n_) \
          (ACC)[mh_*2+m2_][n_] = __builtin_amdgcn_mfma_f32_16x16x32_bf16(pa_[m2_], vb_[n_], (ACC)[mh_*2+m2_][n_], 0, 0, 0); } } \
  } \
} while(0)

// sequential K/V loads into regs (flipped-tail map only bites at g=63)
#define LOADKV(c) do { int c_ = (c); \
  if (c_ < 8){ \
    int p0k_ = g*GS_ + c_*64 + krow_; \
    int p1k_ = p0k_ + 32; \
    int rk0_ = (p0k_ < N_) ? p0k_ : (2*N_ - 1 - p0k_); \
    int rk1_ = (p1k_ < N_) ? p1k_ : (2*N_ - 1 - p1k_); \
    kr0 = *(const us8*)(qkv + (size_t)(b*N_ + rk0_)*1536 + 512 + h*64 + kc8_*8); \
    kr1 = *(const us8*)(qkv + (size_t)(b*N_ + rk1_)*1536 + 512 + h*64 + kc8_*8); \
    int p0v_ = g*GS_ + c_*64 + 2*pair; \
    int p1v_ = p0v_ + 1; \
    int rv0_ = (p0v_ < N_) ? p0v_ : (2*N_ - 1 - p0v_); \
    int rv1_ = (p1v_ < N_) ? p1v_ : (2*N_ - 1 - p1v_); \
    vr0 = *(const us8*)(qkv + (size_t)(b*N_ + rv0_)*1536 + 1024 + h*64 + dvb*8); \
    vr1 = *(const us8*)(qkv + (size_t)(b*N_ + rv1_)*1536 + 1024 + h*64 + dvb*8); \
  } else { \
    kr0 = *(const us8*)(kgb + (size_t)(h*64 + krow_)*64 + kc8_*8); \
    kr1 = *(const us8*)(kgb + (size_t)(h*64 + 32 + krow_)*64 + kc8_*8); \
    vr0 = *(const us8*)(vgb + (size_t)(h*64 + 2*pair)*64 + dvb*8); \
    vr1 = *(const us8*)(vgb + (size_t)(h*64 + 2*pair + 1)*64 + dvb*8); \
  } } while(0)

#define WRITEKV() do { \
  { int r0_ = krow_, r1_ = 32 + krow_; \
    *(us8*)((char*)Kb + ((r0_*128 + kc8_*16) ^ ((r0_ & 7) << 4))) = kr0; \
    *(us8*)((char*)Kb + ((r1_*128 + kc8_*16) ^ ((r1_ & 7) << 4))) = kr1; } \
  _Pragma("unroll") \
  for (int j_ = 0; j_ < 8; ++j_){ \
    int r_ = dvb*8 + j_; \
    int byte_ = (r_*128 + pair*4) ^ ((r_ & 7) << 4); \
    *(unsigned*)((char*)Vb + byte_) = (unsigned)vr0[j_] | ((unsigned)vr1[j_] << 16); } \
} while(0)

// ---------------- fused local(512-window) + global(64) attention ----------------
// R13/R14 structure EXACTLY (best measured: 101us attn). Occupancy structurally
// capped (~190 unified regs/wave); 3-wave budget spills (R4/R10/R15) — do not retry.
__global__ __launch_bounds__(256, 2) void attn_kernel(
    const u16* __restrict__ qkv,   // [B*N][1536] bf16, permuted order (q pre-scaled)
    const u16* __restrict__ kgb,   // [H][64][64] bf16
    const u16* __restrict__ vgb,   // [H][64][64] bf16
    u16* __restrict__ outp)        // [B*N][512] bf16, permuted order
{
  __shared__ u16 Pl[4][32*64];     // 16KB wave-private P / out staging (4KB each)
  __shared__ u16 Kb[64*64];        // 8KB swizzled
  __shared__ u16 Vb[64*64];        // 8KB transposed [dv][t], swizzled

  const int tid = threadIdx.x;
  const int l = tid & 63, w = tid >> 6;
  const int lr = l & 15, lg = l >> 4;
  const int pair = tid & 31, dvb = tid >> 5;
  const int krow_ = tid >> 3, kc8_ = tid & 7;

  const int g = blockIdx.x, h = blockIdx.y, b = blockIdx.z;

  // ---- Q fragments straight to registers ----
  bf16x8 qf[4][2];
#pragma unroll
  for (int m = 0; m < 4; ++m){
    int grow = g*GS_ + w*64 + m*16 + lr;
    const u16* qrow = qkv + (size_t)(b*N_ + grow)*1536 + h*64;
#pragma unroll
    for (int ks = 0; ks < 2; ++ks)
      qf[m][ks] = *(const bf16x8*)(qrow + ks*32 + lg*8);
  }

  u16* Pw = Pl[w];                       // wave-private 4KB [32][64] region

  us8 kr0, kr1, vr0, vr1;
  LOADKV(0);
  WRITEKV();                             // one-time exposed vmcnt wait
  __syncthreads();                       // chunk 0 visible

  f32x4 oacc[4][4];
  float lrun[4];
#pragma unroll
  for (int m = 0; m < 4; ++m)
#pragma unroll
    for (int n = 0; n < 4; ++n) oacc[m][n] = (f32x4){0.f,0.f,0.f,0.f};
#pragma unroll
  for (int m = 0; m < 4; ++m) lrun[m] = 0.f;

  for (int c = 0; c < 8; ++c){
    LOADKV(c + 1);                       // c==7 loads global K/V; in flight across compute
    COMPUTE_CHUNK(Kb, Vb, oacc, lrun);
    __syncthreads();                     // all waves done reading Kb/Vb
    WRITEKV();                           // vmcnt wait covered by the compute above
    __syncthreads();                     // next chunk visible
  }

  // ---- finalize local softmax: reduce lane-partial sums, broadcast, divide ----
  float i1[4];
#pragma unroll
  for (int m = 0; m < 4; ++m){
    float s1 = lrun[m];
    s1 += __shfl_xor(s1, 16); s1 += __shfl_xor(s1, 32);
    i1[m] = 1.f / s1;
  }
#pragma unroll
  for (int m = 0; m < 4; ++m)
#pragma unroll
    for (int j = 0; j < 4; ++j){
      float invb = __shfl(i1[m], lg*4 + j);
#pragma unroll
      for (int n = 0; n < 4; ++n) oacc[m][n][j] *= invb;
    }

  // ---- global-attention chunk (chunk 8, resident in Kb/Vb); swapped QK,
  //      lane-uniform inline normalize, accumulate into oacc ----
  {
    f32x4 s_[4][4];
#pragma unroll
    for (int n_ = 0; n_ < 4; ++n_)
#pragma unroll
      for (int m_ = 0; m_ < 4; ++m_) s_[n_][m_] = (f32x4){0.f,0.f,0.f,0.f};
#pragma unroll
    for (int ks_ = 0; ks_ < 2; ++ks_){
      bf16x8 kf_[4];
#pragma unroll
      for (int n_ = 0; n_ < 4; ++n_) kf_[n_] = lds_read8(Kb, n_*16 + lr, ks_*64 + lg*16);
#pragma unroll
      for (int n_ = 0; n_ < 4; ++n_)
#pragma unroll
        for (int m_ = 0; m_ < 4; ++m_)
          s_[n_][m_] = __builtin_amdgcn_mfma_f32_16x16x32_bf16(kf_[n_], qf[m_][ks_], s_[n_][m_], 0, 0, 0);
    }
#pragma unroll
    for (int m_ = 0; m_ < 4; ++m_){
      float rs_ = 0.f;
#pragma unroll
      for (int n_ = 0; n_ < 4; ++n_)
#pragma unroll
        for (int j_ = 0; j_ < 4; ++j_){
          float p_ = exp2f(s_[n_][m_][j_]); s_[n_][m_][j_] = p_; rs_ += p_;
        }
      rs_ += __shfl_xor(rs_, 16); rs_ += __shfl_xor(rs_, 32);
      float iv_ = 1.f / rs_;               // lane-uniform for q = m*16 + lr
#pragma unroll
      for (int n_ = 0; n_ < 4; ++n_)
#pragma unroll
        for (int j_ = 0; j_ < 4; ++j_) s_[n_][m_][j_] *= iv_;
    }
#pragma unroll
    for (int mh_ = 0; mh_ < 2; ++mh_){
#pragma unroll
      for (int m2_ = 0; m2_ < 2; ++m2_){
        int m_ = mh_*2 + m2_;
        int q_ = m2_*16 + lr;
#pragma unroll
        for (int n_ = 0; n_ < 4; ++n_){
          u32x2 pk_;
          pk_[0] = pk2(s_[n_][m_][0], s_[n_][m_][1]);
          pk_[1] = pk2(s_[n_][m_][2], s_[n_][m_][3]);
          int byte_ = (q_*128 + n_*32 + lg*8) ^ ((q_ & 7) << 4);
          *(u32x2*)((char*)Pw + byte_) = pk_;
        }
      }
#pragma unroll
      for (int ks_ = 0; ks_ < 2; ++ks_){
        bf16x8 pa_[2], vb_[4];
#pragma unroll
        for (int m2_ = 0; m2_ < 2; ++m2_) pa_[m2_] = lds_read8(Pw, m2_*16 + lr, ks_*64 + lg*16);
#pragma unroll
        for (int n_ = 0; n_ < 4; ++n_) vb_[n_] = lds_read8(Vb, n_*16 + lr, ks_*64 + lg*16);
#pragma unroll
        for (int m2_ = 0; m2_ < 2; ++m2_)
#pragma unroll
          for (int n_ = 0; n_ < 4; ++n_)
            oacc[mh_*2+m2_][n_] = __builtin_amdgcn_mfma_f32_16x16x32_bf16(pa_[m2_], vb_[n_], oacc[mh_*2+m2_][n_], 0, 0, 0);
      }
    }
  }

  // ---- epilogue: stage half to LDS, coalesced sequential write, twice ----
#pragma unroll
  for (int mh = 0; mh < 2; ++mh){
#pragma unroll
    for (int m2 = 0; m2 < 2; ++m2)
#pragma unroll
      for (int n = 0; n < 4; ++n)
#pragma unroll
        for (int j = 0; j < 4; ++j){
          int row = m2*16 + lg*4 + j, col = n*16 + lr;
          int byte = (row*128 + col*2) ^ ((row & 7) << 4);
          *(u16*)((char*)Pw + byte) = f2bh(oacc[mh*2+m2][n][j]);
        }
    __builtin_amdgcn_s_waitcnt(0);  // drain before re-reading wave-private Pw
#pragma unroll
    for (int i4 = 0; i4 < 4; ++i4){
      int o = i4*1024 + l*16;
      int row = o >> 7, c8 = (o & 127) >> 4;
      int addr = o ^ ((row & 7) << 4);
      u32x4 d = *(const u32x4*)((const char*)Pw + addr);
      int orow = g*GS_ + w*64 + mh*32 + row;
      *(u32x4*)(outp + (size_t)(b*N_ + orow)*512 + h*64 + c8*8) = d;
    }
  }
}

extern "C" void kernel_launch(void* const* d_in, const int* in_sizes, int n_in,
                              void* d_out, int out_size, void* d_ws, size_t ws_size,
                              hipStream_t stream)
{
  const float* x  = (const float*)d_in[0];
  const int*  idx = (const int*)d_in[1];
  const float* kg = (const float*)d_in[2];
  const float* vg = (const float*)d_in[3];
  const float* Wq = (const float*)d_in[4];
  const float* Wk = (const float*)d_in[5];
  const float* Wv = (const float*)d_in[6];
  const float* Wp = (const float*)d_in[7];
  float* out = (float*)d_out;

  char* ws = (char*)d_ws;
  u16* Xb   = (u16*)ws;                                   // reused as attn_o
  u16* qkv  = (u16*)(ws + 33554432);
  u16* Wqt  = (u16*)(ws + 134217728);
  u16* Wkt  = (u16*)(ws + 134217728 + 524288);
  u16* Wvt  = (u16*)(ws + 134217728 + 2*524288);
  u16* Wpt  = (u16*)(ws + 134217728 + 3*524288);
  u16* kgb  = (u16*)(ws + 134217728 + 4*524288);
  u16* vgb  = (u16*)(ws + 134217728 + 4*524288 + 65536);
  u16* attn_o = Xb;  // safe: gemm_qkv (reads Xb) completes before attn writes

  cvt_f32_bf16<<<16384, 256, 0, stream>>>((const float4*)x, (us4*)Xb, 16777216/4);
  cvt_kv<<<dim3(32,2), 256, 0, stream>>>((const float4*)kg, (const float4*)vg,
                                         (us4*)kgb, (us4*)vgb);
  cvt_w_t<<<dim3(32,32,4), 256, 0, stream>>>(Wq, Wk, Wv, Wp, Wqt, Wkt, Wvt, Wpt);
  // qkv GEMM: bn-fastest grid, BK=32 dbuf prefetch; gathers A-rows via idx
  gemm_bf16k<u16, true, true, false><<<dim3(12,256), 256, 0, stream>>>(Xb, Wqt, Wkt, Wvt, idx, qkv, 1536);
  // attention: R14 structure (best measured)
  attn_kernel<<<dim3(64,8,2), 256, 0, stream>>>(qkv, kgb, vgb, attn_o);
  // proj GEMM: bn-fastest grid, BK=32 dbuf prefetch; scatters C-rows via idx
  gemm_bf16k<float, false, false, true><<<dim3(4,256), 256, 0, stream>>>(attn_o, Wpt, Wpt, Wpt, idx, out, 512);
}

// Round 19
// 206.785 us; speedup vs baseline: 1.5075x; 1.0210x over previous
//
#include <hip/hip_runtime.h>
#include <hip/hip_bf16.h>

#define B_   2
#define N_   16384
#define H_   8
#define GS_  256
#define NG_  64

typedef unsigned short u16;
typedef __attribute__((ext_vector_type(8))) short bf16x8;
typedef __attribute__((ext_vector_type(4))) float f32x4;
typedef __attribute__((ext_vector_type(8))) unsigned short us8;
typedef __attribute__((ext_vector_type(4))) unsigned short us4;
typedef __attribute__((ext_vector_type(4))) unsigned int u32x4;
typedef __attribute__((ext_vector_type(2))) unsigned int u32x2;

__device__ __forceinline__ u16 f2b(float f){
  union { float f; unsigned u; } v; v.f = f;
  unsigned r = v.u + 0x7fffu + ((v.u >> 16) & 1u);
  return (u16)(r >> 16);
}

__device__ __forceinline__ u16 f2bh(float f){
  __hip_bfloat16 h = __float2bfloat16(f);
  u16 u; __builtin_memcpy(&u, &h, 2);
  return u;
}

// pack two floats into one u32 of 2 bf16 (lo = a, hi = b) — HW packed convert
__device__ __forceinline__ unsigned pk2(float a, float b){
  unsigned r;
  asm("v_cvt_pk_bf16_f32 %0, %1, %2" : "=v"(r) : "v"(a), "v"(b));
  return r;
}

__device__ __forceinline__ void gload16(const void* g, const void* lds){
  __builtin_amdgcn_global_load_lds(
      (const __attribute__((address_space(1))) void*)g,
      (__attribute__((address_space(3))) void*)lds, 16, 0, 0);
}

// swizzled 16B fragment read from a [rows][64] bf16 tile (row stride 128B)
__device__ __forceinline__ bf16x8 lds_read8(const u16* base, int row, int coloff){
  int byte = (row*128 + coloff) ^ ((row & 7) << 4);
  return *(const bf16x8*)((const char*)base + byte);
}

__device__ __forceinline__ void stout(float* p, float v){ *p = v; }
__device__ __forceinline__ void stout(u16* p, float v){ *p = f2b(v); }

// ---------------- fp32 -> bf16 vector convert (x) ----------------
__global__ void cvt_f32_bf16(const float4* __restrict__ in, us4* __restrict__ out, int n4){
  int i = blockIdx.x * 256 + threadIdx.x;
  if (i < n4){
    float4 v = in[i];
    us4 o;
    o[0] = f2b(v.x); o[1] = f2b(v.y); o[2] = f2b(v.z); o[3] = f2b(v.w);
    out[i] = o;
  }
}

// merged small convert: y=0 -> kg, y=1 -> vg
__global__ void cvt_kv(const float4* __restrict__ kg, const float4* __restrict__ vg,
                       us4* __restrict__ ok, us4* __restrict__ ov){
  int i = blockIdx.x * 256 + threadIdx.x;
  const float4* in = blockIdx.y ? vg : kg;
  us4* out = blockIdx.y ? ov : ok;
  float4 v = in[i];
  us4 o;
  o[0] = f2b(v.x); o[1] = f2b(v.y); o[2] = f2b(v.z); o[3] = f2b(v.w);
  out[i] = o;
}

// ---------------- weight convert + transpose: T[n][k] = bf16(W[k][n]) ----------------
__global__ void cvt_w_t(const float* __restrict__ W0, const float* __restrict__ W1,
                        const float* __restrict__ W2, const float* __restrict__ W3,
                        u16* __restrict__ T0, u16* __restrict__ T1,
                        u16* __restrict__ T2, u16* __restrict__ T3)
{
  int z = blockIdx.z;
  const float* W = (z==0)?W0:((z==1)?W1:((z==2)?W2:W3));
  u16* T = (z==0)?T0:((z==1)?T1:((z==2)?T2:T3));
  __shared__ float tile[16][17];
  int tx = threadIdx.x & 15, ty = threadIdx.x >> 4;
  int k0 = blockIdx.x*16, n0 = blockIdx.y*16;
  tile[ty][tx] = W[(k0+ty)*512 + n0 + tx];
  __syncthreads();
  T[(n0+ty)*512 + k0 + tx] = f2b(tile[tx][ty]);
}

// ---------------- bf16 GEMM: C = A @ Wt^T (R13 best: single-buffer BK=64) ----------------
// Bracketed schedule optimum for this 128-tile structure: single-buffer BK=64
// (57us qkv) < BK=32 dbuf (+6us, R18) < BK=64 dbuf 64KB (+9us, R17).
// bn-fastest grid. GATHA: A-rows gathered via perm. SCATC: C-rows scattered.
template<typename OUT_T, bool MULTI, bool GATHA, bool SCATC>
__global__ __launch_bounds__(256, 2) void gemm_bf16k(
    const u16* __restrict__ A,
    const u16* __restrict__ Wt0, const u16* __restrict__ Wt1, const u16* __restrict__ Wt2,
    const int* __restrict__ perm,   // [B][N] permutation
    OUT_T* __restrict__ C, int ldc)
{
  __shared__ u16 Al[128*64];
  __shared__ u16 Bl[128*64];
  const int tid = threadIdx.x;
  const int l = tid & 63, w = tid >> 6;
  const int lr = l & 15, lg = l >> 4;
  const int bm = blockIdx.y, bn = blockIdx.x;   // bn fastest
  const int wr = (w >> 1) * 64, wc = (w & 1) * 64;

  const u16* Wt; int ocolb; float qsc;
  if (MULTI){
    int wsel = bn >> 2;
    Wt = (wsel == 0) ? Wt0 : ((wsel == 1) ? Wt1 : Wt2);
    ocolb = (bn & 3) * 128;
    qsc = (wsel == 0) ? 0.18033688f : 1.0f;   // 0.125 * log2(e)
  } else { Wt = Wt0; ocolb = bn * 128; qsc = 1.0f; }

  // per-thread A-row indices (4 rows), gather-translated once
  int arows[4];
#pragma unroll
  for (int i = 0; i < 4; ++i){
    int r = bm*128 + i*32 + (tid >> 3);
    arows[i] = GATHA ? ((r & ~(N_-1)) + perm[r]) : r;
  }

  f32x4 acc[4][4];
#pragma unroll
  for (int m = 0; m < 4; ++m)
#pragma unroll
    for (int n = 0; n < 4; ++n) acc[m][n] = (f32x4){0.f,0.f,0.f,0.f};

  const int c8 = tid & 7;
  for (int kk = 0; kk < 512; kk += 64){
#pragma unroll
    for (int i = 0; i < 4; ++i){
      int o = i*4096 + tid*16;
      int brow = o >> 7;
      gload16(A  + (size_t)arows[i]*512 + kk + c8*8, (const char*)Al + i*4096 + w*1024);
      gload16(Wt + (size_t)(ocolb + brow)*512 + kk + c8*8, (const char*)Bl + i*4096 + w*1024);
    }
    __syncthreads();
#pragma unroll
    for (int ks = 0; ks < 2; ++ks){
      bf16x8 af[4], bfv[4];
#pragma unroll
      for (int m = 0; m < 4; ++m) af[m]  = *(const bf16x8*)&Al[(wr + m*16 + lr)*64 + ks*32 + lg*8];
#pragma unroll
      for (int n = 0; n < 4; ++n) bfv[n] = *(const bf16x8*)&Bl[(wc + n*16 + lr)*64 + ks*32 + lg*8];
#pragma unroll
      for (int m = 0; m < 4; ++m)
#pragma unroll
        for (int n = 0; n < 4; ++n)
          acc[m][n] = __builtin_amdgcn_mfma_f32_16x16x32_bf16(af[m], bfv[n], acc[m][n], 0, 0, 0);
    }
    __syncthreads();
  }
#pragma unroll
  for (int m = 0; m < 4; ++m)
#pragma unroll
    for (int n = 0; n < 4; ++n)
#pragma unroll
      for (int j = 0; j < 4; ++j){
        int row = bm*128 + wr + m*16 + lg*4 + j;
        int col = bn*128 + wc + n*16 + lr;
        size_t orow = SCATC ? (size_t)((row & ~(N_-1)) + perm[row]) : (size_t)row;
        stout(&C[orow*ldc + col], acc[m][n][j] * qsc);
      }
}

// ---- attention compute, SWAPPED QK (S^T = mfma(K,Q)) + packed-b64 P stores ----
#define COMPUTE_CHUNK(KBUF, VBUF, ACC, LAC) do { \
  f32x4 s_[4][4]; \
  _Pragma("unroll") \
  for (int n_ = 0; n_ < 4; ++n_){ _Pragma("unroll") for (int m_ = 0; m_ < 4; ++m_) s_[n_][m_] = (f32x4){0.f,0.f,0.f,0.f}; } \
  _Pragma("unroll") \
  for (int ks_ = 0; ks_ < 2; ++ks_){ \
    bf16x8 kf_[4]; \
    _Pragma("unroll") for (int n_ = 0; n_ < 4; ++n_) kf_[n_] = lds_read8((KBUF), n_*16 + lr, ks_*64 + lg*16); \
    _Pragma("unroll") for (int n_ = 0; n_ < 4; ++n_){ \
      _Pragma("unroll") for (int m_ = 0; m_ < 4; ++m_) \
        s_[n_][m_] = __builtin_amdgcn_mfma_f32_16x16x32_bf16(kf_[n_], qf[m_][ks_], s_[n_][m_], 0, 0, 0); } } \
  _Pragma("unroll") \
  for (int m_ = 0; m_ < 4; ++m_){ \
    float rs_ = 0.f; \
    _Pragma("unroll") for (int n_ = 0; n_ < 4; ++n_){ \
      _Pragma("unroll") for (int j_ = 0; j_ < 4; ++j_){ \
        float p_ = exp2f(s_[n_][m_][j_]); s_[n_][m_][j_] = p_; rs_ += p_; } } \
    (LAC)[m_] += rs_; } \
  _Pragma("unroll") \
  for (int mh_ = 0; mh_ < 2; ++mh_){ \
    _Pragma("unroll") for (int m2_ = 0; m2_ < 2; ++m2_){ \
      int m_ = mh_*2 + m2_; \
      int q_ = m2_*16 + lr; \
      _Pragma("unroll") for (int n_ = 0; n_ < 4; ++n_){ \
        u32x2 pk_; \
        pk_[0] = pk2(s_[n_][m_][0], s_[n_][m_][1]); \
        pk_[1] = pk2(s_[n_][m_][2], s_[n_][m_][3]); \
        int byte_ = (q_*128 + n_*32 + lg*8) ^ ((q_ & 7) << 4); \
        *(u32x2*)((char*)Pw + byte_) = pk_; } } \
    _Pragma("unroll") for (int ks_ = 0; ks_ < 2; ++ks_){ \
      bf16x8 pa_[2], vb_[4]; \
      _Pragma("unroll") for (int m2_ = 0; m2_ < 2; ++m2_) pa_[m2_] = lds_read8(Pw, m2_*16 + lr, ks_*64 + lg*16); \
      _Pragma("unroll") for (int n_ = 0; n_ < 4; ++n_) vb_[n_] = lds_read8((VBUF), n_*16 + lr, ks_*64 + lg*16); \
      _Pragma("unroll") for (int m2_ = 0; m2_ < 2; ++m2_){ \
        _Pragma("unroll") for (int n_ = 0; n_ < 4; ++n_) \
          (ACC)[mh_*2+m2_][n_] = __builtin_amdgcn_mfma_f32_16x16x32_bf16(pa_[m2_], vb_[n_], (ACC)[mh_*2+m2_][n_], 0, 0, 0); } } \
  } \
} while(0)

// sequential K/V loads into regs (flipped-tail map only bites at g=63)
#define LOADKV(c) do { int c_ = (c); \
  if (c_ < 8){ \
    int p0k_ = g*GS_ + c_*64 + krow_; \
    int p1k_ = p0k_ + 32; \
    int rk0_ = (p0k_ < N_) ? p0k_ : (2*N_ - 1 - p0k_); \
    int rk1_ = (p1k_ < N_) ? p1k_ : (2*N_ - 1 - p1k_); \
    kr0 = *(const us8*)(qkv + (size_t)(b*N_ + rk0_)*1536 + 512 + h*64 + kc8_*8); \
    kr1 = *(const us8*)(qkv + (size_t)(b*N_ + rk1_)*1536 + 512 + h*64 + kc8_*8); \
    int p0v_ = g*GS_ + c_*64 + 2*pair; \
    int p1v_ = p0v_ + 1; \
    int rv0_ = (p0v_ < N_) ? p0v_ : (2*N_ - 1 - p0v_); \
    int rv1_ = (p1v_ < N_) ? p1v_ : (2*N_ - 1 - p1v_); \
    vr0 = *(const us8*)(qkv + (size_t)(b*N_ + rv0_)*1536 + 1024 + h*64 + dvb*8); \
    vr1 = *(const us8*)(qkv + (size_t)(b*N_ + rv1_)*1536 + 1024 + h*64 + dvb*8); \
  } else { \
    kr0 = *(const us8*)(kgb + (size_t)(h*64 + krow_)*64 + kc8_*8); \
    kr1 = *(const us8*)(kgb + (size_t)(h*64 + 32 + krow_)*64 + kc8_*8); \
    vr0 = *(const us8*)(vgb + (size_t)(h*64 + 2*pair)*64 + dvb*8); \
    vr1 = *(const us8*)(vgb + (size_t)(h*64 + 2*pair + 1)*64 + dvb*8); \
  } } while(0)

#define WRITEKV() do { \
  { int r0_ = krow_, r1_ = 32 + krow_; \
    *(us8*)((char*)Kb + ((r0_*128 + kc8_*16) ^ ((r0_ & 7) << 4))) = kr0; \
    *(us8*)((char*)Kb + ((r1_*128 + kc8_*16) ^ ((r1_ & 7) << 4))) = kr1; } \
  _Pragma("unroll") \
  for (int j_ = 0; j_ < 8; ++j_){ \
    int r_ = dvb*8 + j_; \
    int byte_ = (r_*128 + pair*4) ^ ((r_ & 7) << 4); \
    *(unsigned*)((char*)Vb + byte_) = (unsigned)vr0[j_] | ((unsigned)vr1[j_] << 16); } \
} while(0)

// ---------------- fused local(512-window) + global(64) attention ----------------
// R13/R14 structure EXACTLY (best measured: ~101us attn; 32KB LDS, single K/V
// buffer, 2 barriers/chunk, HW cvt_pk P-pack). Occupancy structurally capped
// (~190 unified regs/wave); 3-wave budget spills (R4/R10/R15) — do not retry.
__global__ __launch_bounds__(256, 2) void attn_kernel(
    const u16* __restrict__ qkv,   // [B*N][1536] bf16, permuted order (q pre-scaled)
    const u16* __restrict__ kgb,   // [H][64][64] bf16
    const u16* __restrict__ vgb,   // [H][64][64] bf16
    u16* __restrict__ outp)        // [B*N][512] bf16, permuted order
{
  __shared__ u16 Pl[4][32*64];     // 16KB wave-private P / out staging (4KB each)
  __shared__ u16 Kb[64*64];        // 8KB swizzled
  __shared__ u16 Vb[64*64];        // 8KB transposed [dv][t], swizzled

  const int tid = threadIdx.x;
  const int l = tid & 63, w = tid >> 6;
  const int lr = l & 15, lg = l >> 4;
  const int pair = tid & 31, dvb = tid >> 5;
  const int krow_ = tid >> 3, kc8_ = tid & 7;

  const int g = blockIdx.x, h = blockIdx.y, b = blockIdx.z;

  // ---- Q fragments straight to registers ----
  bf16x8 qf[4][2];
#pragma unroll
  for (int m = 0; m < 4; ++m){
    int grow = g*GS_ + w*64 + m*16 + lr;
    const u16* qrow = qkv + (size_t)(b*N_ + grow)*1536 + h*64;
#pragma unroll
    for (int ks = 0; ks < 2; ++ks)
      qf[m][ks] = *(const bf16x8*)(qrow + ks*32 + lg*8);
  }

  u16* Pw = Pl[w];                       // wave-private 4KB [32][64] region

  us8 kr0, kr1, vr0, vr1;
  LOADKV(0);
  WRITEKV();                             // one-time exposed vmcnt wait
  __syncthreads();                       // chunk 0 visible

  f32x4 oacc[4][4];
  float lrun[4];
#pragma unroll
  for (int m = 0; m < 4; ++m)
#pragma unroll
    for (int n = 0; n < 4; ++n) oacc[m][n] = (f32x4){0.f,0.f,0.f,0.f};
#pragma unroll
  for (int m = 0; m < 4; ++m) lrun[m] = 0.f;

  for (int c = 0; c < 8; ++c){
    LOADKV(c + 1);                       // c==7 loads global K/V; in flight across compute
    COMPUTE_CHUNK(Kb, Vb, oacc, lrun);
    __syncthreads();                     // all waves done reading Kb/Vb
    WRITEKV();                           // vmcnt wait covered by the compute above
    __syncthreads();                     // next chunk visible
  }

  // ---- finalize local softmax: reduce lane-partial sums, broadcast, divide ----
  float i1[4];
#pragma unroll
  for (int m = 0; m < 4; ++m){
    float s1 = lrun[m];
    s1 += __shfl_xor(s1, 16); s1 += __shfl_xor(s1, 32);
    i1[m] = 1.f / s1;
  }
#pragma unroll
  for (int m = 0; m < 4; ++m)
#pragma unroll
    for (int j = 0; j < 4; ++j){
      float invb = __shfl(i1[m], lg*4 + j);
#pragma unroll
      for (int n = 0; n < 4; ++n) oacc[m][n][j] *= invb;
    }

  // ---- global-attention chunk (chunk 8, resident in Kb/Vb); swapped QK,
  //      lane-uniform inline normalize, accumulate into oacc ----
  {
    f32x4 s_[4][4];
#pragma unroll
    for (int n_ = 0; n_ < 4; ++n_)
#pragma unroll
      for (int m_ = 0; m_ < 4; ++m_) s_[n_][m_] = (f32x4){0.f,0.f,0.f,0.f};
#pragma unroll
    for (int ks_ = 0; ks_ < 2; ++ks_){
      bf16x8 kf_[4];
#pragma unroll
      for (int n_ = 0; n_ < 4; ++n_) kf_[n_] = lds_read8(Kb, n_*16 + lr, ks_*64 + lg*16);
#pragma unroll
      for (int n_ = 0; n_ < 4; ++n_)
#pragma unroll
        for (int m_ = 0; m_ < 4; ++m_)
          s_[n_][m_] = __builtin_amdgcn_mfma_f32_16x16x32_bf16(kf_[n_], qf[m_][ks_], s_[n_][m_], 0, 0, 0);
    }
#pragma unroll
    for (int m_ = 0; m_ < 4; ++m_){
      float rs_ = 0.f;
#pragma unroll
      for (int n_ = 0; n_ < 4; ++n_)
#pragma unroll
        for (int j_ = 0; j_ < 4; ++j_){
          float p_ = exp2f(s_[n_][m_][j_]); s_[n_][m_][j_] = p_; rs_ += p_;
        }
      rs_ += __shfl_xor(rs_, 16); rs_ += __shfl_xor(rs_, 32);
      float iv_ = 1.f / rs_;               // lane-uniform for q = m*16 + lr
#pragma unroll
      for (int n_ = 0; n_ < 4; ++n_)
#pragma unroll
        for (int j_ = 0; j_ < 4; ++j_) s_[n_][m_][j_] *= iv_;
    }
#pragma unroll
    for (int mh_ = 0; mh_ < 2; ++mh_){
#pragma unroll
      for (int m2_ = 0; m2_ < 2; ++m2_){
        int m_ = mh_*2 + m2_;
        int q_ = m2_*16 + lr;
#pragma unroll
        for (int n_ = 0; n_ < 4; ++n_){
          u32x2 pk_;
          pk_[0] = pk2(s_[n_][m_][0], s_[n_][m_][1]);
          pk_[1] = pk2(s_[n_][m_][2], s_[n_][m_][3]);
          int byte_ = (q_*128 + n_*32 + lg*8) ^ ((q_ & 7) << 4);
          *(u32x2*)((char*)Pw + byte_) = pk_;
        }
      }
#pragma unroll
      for (int ks_ = 0; ks_ < 2; ++ks_){
        bf16x8 pa_[2], vb_[4];
#pragma unroll
        for (int m2_ = 0; m2_ < 2; ++m2_) pa_[m2_] = lds_read8(Pw, m2_*16 + lr, ks_*64 + lg*16);
#pragma unroll
        for (int n_ = 0; n_ < 4; ++n_) vb_[n_] = lds_read8(Vb, n_*16 + lr, ks_*64 + lg*16);
#pragma unroll
        for (int m2_ = 0; m2_ < 2; ++m2_)
#pragma unroll
          for (int n_ = 0; n_ < 4; ++n_)
            oacc[mh_*2+m2_][n_] = __builtin_amdgcn_mfma_f32_16x16x32_bf16(pa_[m2_], vb_[n_], oacc[mh_*2+m2_][n_], 0, 0, 0);
      }
    }
  }

  // ---- epilogue: stage half to LDS, coalesced sequential write, twice ----
#pragma unroll
  for (int mh = 0; mh < 2; ++mh){
#pragma unroll
    for (int m2 = 0; m2 < 2; ++m2)
#pragma unroll
      for (int n = 0; n < 4; ++n)
#pragma unroll
        for (int j = 0; j < 4; ++j){
          int row = m2*16 + lg*4 + j, col = n*16 + lr;
          int byte = (row*128 + col*2) ^ ((row & 7) << 4);
          *(u16*)((char*)Pw + byte) = f2bh(oacc[mh*2+m2][n][j]);
        }
    __builtin_amdgcn_s_waitcnt(0);  // drain before re-reading wave-private Pw
#pragma unroll
    for (int i4 = 0; i4 < 4; ++i4){
      int o = i4*1024 + l*16;
      int row = o >> 7, c8 = (o & 127) >> 4;
      int addr = o ^ ((row & 7) << 4);
      u32x4 d = *(const u32x4*)((const char*)Pw + addr);
      int orow = g*GS_ + w*64 + mh*32 + row;
      *(u32x4*)(outp + (size_t)(b*N_ + orow)*512 + h*64 + c8*8) = d;
    }
  }
}

extern "C" void kernel_launch(void* const* d_in, const int* in_sizes, int n_in,
                              void* d_out, int out_size, void* d_ws, size_t ws_size,
                              hipStream_t stream)
{
  const float* x  = (const float*)d_in[0];
  const int*  idx = (const int*)d_in[1];
  const float* kg = (const float*)d_in[2];
  const float* vg = (const float*)d_in[3];
  const float* Wq = (const float*)d_in[4];
  const float* Wk = (const float*)d_in[5];
  const float* Wv = (const float*)d_in[6];
  const float* Wp = (const float*)d_in[7];
  float* out = (float*)d_out;

  char* ws = (char*)d_ws;
  u16* Xb   = (u16*)ws;                                   // reused as attn_o
  u16* qkv  = (u16*)(ws + 33554432);
  u16* Wqt  = (u16*)(ws + 134217728);
  u16* Wkt  = (u16*)(ws + 134217728 + 524288);
  u16* Wvt  = (u16*)(ws + 134217728 + 2*524288);
  u16* Wpt  = (u16*)(ws + 134217728 + 3*524288);
  u16* kgb  = (u16*)(ws + 134217728 + 4*524288);
  u16* vgb  = (u16*)(ws + 134217728 + 4*524288 + 65536);
  u16* attn_o = Xb;  // safe: gemm_qkv (reads Xb) completes before attn writes

  cvt_f32_bf16<<<16384, 256, 0, stream>>>((const float4*)x, (us4*)Xb, 16777216/4);
  cvt_kv<<<dim3(32,2), 256, 0, stream>>>((const float4*)kg, (const float4*)vg,
                                         (us4*)kgb, (us4*)vgb);
  cvt_w_t<<<dim3(32,32,4), 256, 0, stream>>>(Wq, Wk, Wv, Wp, Wqt, Wkt, Wvt, Wpt);
  // qkv GEMM: bn-fastest grid, single-buffer BK=64 (bracketed optimum);
  // gathers A-rows via idx -> qkv in PERMUTED order (q pre-scaled 0.125*log2e)
  gemm_bf16k<u16, true, true, false><<<dim3(12,256), 256, 0, stream>>>(Xb, Wqt, Wkt, Wvt, idx, qkv, 1536);
  // attention: R13/R14 structure (best measured)
  attn_kernel<<<dim3(64,8,2), 256, 0, stream>>>(qkv, kgb, vgb, attn_o);
  // proj GEMM: bn-fastest grid; scatters C-rows via idx -> token order
  gemm_bf16k<float, false, false, true><<<dim3(4,256), 256, 0, stream>>>(attn_o, Wpt, Wpt, Wpt, idx, out, 512);
}